// Round 1
// baseline (675.087 us; speedup 1.0000x reference)
//
#include <hip/hip_runtime.h>
#include <math.h>

#define NN 50000
#define E0 640000
#define ET 690000   // E0 + NN self loops
#define F1 128
#define D1 256      // 8 heads * 32
#define C2 16

// ---------------- Layer-1 GEMM: xl = x@W1l, xr = x@W1r ----------------
// Block: 8 nodes x 256 cols. x tile staged transposed in LDS.
__global__ __launch_bounds__(256) void k_gemm1(
    const float* __restrict__ x, const float* __restrict__ Wl,
    const float* __restrict__ Wr, float* __restrict__ xl, float* __restrict__ xr) {
  const float* W = blockIdx.y ? Wr : Wl;
  float* out = blockIdx.y ? xr : xl;
  __shared__ float lds[F1 * 8];
  const int n0 = blockIdx.x * 8;
  const int t = threadIdx.x;
  for (int idx = t; idx < 8 * F1; idx += 256) {
    int i = idx >> 7, k = idx & 127;
    lds[k * 8 + i] = x[(size_t)(n0 + i) * F1 + k];
  }
  __syncthreads();
  float acc[8];
#pragma unroll
  for (int i = 0; i < 8; ++i) acc[i] = 0.f;
#pragma unroll 4
  for (int k = 0; k < F1; ++k) {
    float w = W[k * D1 + t];
    const float4 a0 = *(const float4*)&lds[k * 8];
    const float4 a1 = *(const float4*)&lds[k * 8 + 4];
    acc[0] += a0.x * w; acc[1] += a0.y * w; acc[2] += a0.z * w; acc[3] += a0.w * w;
    acc[4] += a1.x * w; acc[5] += a1.y * w; acc[6] += a1.z * w; acc[7] += a1.w * w;
  }
#pragma unroll
  for (int i = 0; i < 8; ++i) out[(size_t)(n0 + i) * D1 + t] = acc[i];
}

// ---------------- CSR build ----------------
__global__ void k_hist(const int* __restrict__ ei, int* __restrict__ deg) {
  int e = blockIdx.x * 256 + threadIdx.x;
  if (e >= ET) return;
  int d = (e < E0) ? ei[E0 + e] : (e - E0);
  atomicAdd(&deg[d], 1);
}

__global__ __launch_bounds__(1024) void k_scan(const int* __restrict__ deg,
                                               int* __restrict__ offs) {
  __shared__ int lds[1024];
  const int t = threadIdx.x;
  const int CH = (NN + 1023) / 1024;  // 49
  int start = t * CH;
  int end = start + CH; if (end > NN) end = NN;
  int sum = 0;
  for (int i = start; i < end && i < NN; ++i) sum += deg[i];
  lds[t] = sum;
  __syncthreads();
  for (int off = 1; off < 1024; off <<= 1) {
    int v = (t >= off) ? lds[t - off] : 0;
    __syncthreads();
    lds[t] += v;
    __syncthreads();
  }
  int run = lds[t] - sum;  // exclusive prefix
  for (int i = start; i < end && i < NN; ++i) { offs[i] = run; run += deg[i]; }
  if (t == 1023) offs[NN] = lds[1023];
}

__global__ void k_cursor(const int* __restrict__ offs, int* __restrict__ cur) {
  int i = blockIdx.x * 256 + threadIdx.x;
  if (i < NN) cur[i] = offs[i];
}

__global__ void k_scatter(const int* __restrict__ ei, int* __restrict__ cur,
                          int* __restrict__ csr) {
  int e = blockIdx.x * 256 + threadIdx.x;
  if (e >= ET) return;
  int s, d;
  if (e < E0) { s = ei[e]; d = ei[E0 + e]; } else { s = d = e - E0; }
  int pos = atomicAdd(&cur[d], 1);
  csr[pos] = s;
}

// ---------------- Layer-1 aggregation (online softmax) ----------------
// One block per dst node. t -> (head = t>>5, feat = t&31). Writes ELU(out+b1)
// in place over xr (only this block reads xr[n]).
__global__ __launch_bounds__(256) void k_agg1(
    const float* __restrict__ xl, float* __restrict__ xr_h,
    const int* __restrict__ offs, const int* __restrict__ csr,
    const float* __restrict__ att, const float* __restrict__ b1) {
  const int n = blockIdx.x;
  const int t = threadIdx.x;
  const float xr_v = xr_h[(size_t)n * D1 + t];
  const float att_v = att[t];          // att1 flat [8][32] == t
  float m = -INFINITY, l = 0.f, acc = 0.f;
  const int beg = offs[n], fin = offs[n + 1];
  for (int idx = beg; idx < fin; ++idx) {
    int s = csr[idx];
    float xlv = xl[(size_t)s * D1 + t];
    float v = xlv + xr_v;
    v = v > 0.f ? v : 0.2f * v;          // leaky 0.2
    float c = v * att_v;
    c += __shfl_xor(c, 1);
    c += __shfl_xor(c, 2);
    c += __shfl_xor(c, 4);
    c += __shfl_xor(c, 8);
    c += __shfl_xor(c, 16);              // sum over 32 feats of this head
    float mn = fmaxf(m, c);
    float sc = expf(m - mn);             // m=-inf first iter -> 0
    float p = expf(c - mn);
    l = l * sc + p;
    acc = acc * sc + p * xlv;
    m = mn;
  }
  float o = acc / (l + 1e-16f) + b1[t];
  o = o > 0.f ? o : expm1f(o);           // ELU
  xr_h[(size_t)n * D1 + t] = o;
}

// ---------------- Layer-2 GEMM: h2l = h@W2l, h2r = h@W2r ----------------
// Block: 8 nodes x 32 cols (cols 0..15 -> W2l, 16..31 -> W2r).
__global__ __launch_bounds__(256) void k_gemm2(
    const float* __restrict__ h, const float* __restrict__ W2l,
    const float* __restrict__ W2r, float* __restrict__ h2l,
    float* __restrict__ h2r) {
  __shared__ float lds[D1 * 8];
  const int n0 = blockIdx.x * 8;
  const int t = threadIdx.x;
  for (int idx = t; idx < 8 * D1; idx += 256) {
    int i = idx >> 8, k = idx & 255;
    lds[k * 8 + i] = h[(size_t)(n0 + i) * D1 + k];
  }
  __syncthreads();
  const int i = t >> 5, c = t & 31;
  const float* W = (c < 16) ? W2l : W2r;
  float* out = (c < 16) ? h2l : h2r;
  const int cc = c & 15;
  float acc = 0.f;
#pragma unroll 4
  for (int k = 0; k < D1; ++k) acc += lds[k * 8 + i] * W[k * 16 + cc];
  out[(size_t)(n0 + i) * 16 + cc] = acc;
}

// ---------------- Layer-2 aggregation ----------------
// One wave per node; 4 edges in flight (16-lane groups), merged at the end.
__global__ __launch_bounds__(256) void k_agg2(
    const float* __restrict__ h2l, const float* __restrict__ h2r,
    const int* __restrict__ offs, const int* __restrict__ csr,
    const float* __restrict__ att2, const float* __restrict__ b2,
    float* __restrict__ out) {
  const int wave = threadIdx.x >> 6;
  const int lane = threadIdx.x & 63;
  const int n = blockIdx.x * 4 + wave;
  if (n >= NN) return;
  const int c = lane & 15, g = lane >> 4;
  const float xr_v = h2r[(size_t)n * C2 + c];
  const float att_v = att2[c];
  float m = -INFINITY, l = 0.f, acc = 0.f;
  const int beg = offs[n], fin = offs[n + 1];
  for (int idx = beg + g; idx < fin; idx += 4) {
    int s = csr[idx];
    float xlv = h2l[(size_t)s * C2 + c];
    float v = xlv + xr_v;
    v = v > 0.f ? v : 0.2f * v;
    float sc0 = v * att_v;
    sc0 += __shfl_xor(sc0, 1);
    sc0 += __shfl_xor(sc0, 2);
    sc0 += __shfl_xor(sc0, 4);
    sc0 += __shfl_xor(sc0, 8);           // sum over 16 classes
    float mn = fmaxf(m, sc0);
    float s1 = expf(m - mn);
    float p = expf(sc0 - mn);
    l = l * s1 + p;
    acc = acc * s1 + p * xlv;
    m = mn;
  }
  // merge the 4 groups (xor 16, 32 stay inside the 64-lane wave)
  float M = fmaxf(m, __shfl_xor(m, 16));
  M = fmaxf(M, __shfl_xor(M, 32));
  float sc = expf(m - M);                // empty group: exp(-inf)=0
  l *= sc; acc *= sc;
  l += __shfl_xor(l, 16);  l += __shfl_xor(l, 32);
  acc += __shfl_xor(acc, 16); acc += __shfl_xor(acc, 32);
  float o = acc / (l + 1e-16f) + b2[c];
  o = o > 0.f ? o : 0.01f * o;           // final leaky 0.01
  if (lane < 16) out[(size_t)n * C2 + c] = o;
}

extern "C" void kernel_launch(void* const* d_in, const int* in_sizes, int n_in,
                              void* d_out, int out_size, void* d_ws, size_t ws_size,
                              hipStream_t stream) {
  const float* x    = (const float*)d_in[0];
  const int*   ei   = (const int*)d_in[1];
  const float* W1l  = (const float*)d_in[2];
  const float* W1r  = (const float*)d_in[3];
  const float* att1 = (const float*)d_in[4];
  const float* b1   = (const float*)d_in[5];
  const float* W2l  = (const float*)d_in[6];
  const float* W2r  = (const float*)d_in[7];
  const float* att2 = (const float*)d_in[8];
  const float* b2   = (const float*)d_in[9];
  float* out = (float*)d_out;

  // Workspace layout (~106 MB):
  float* xl = (float*)d_ws;                       // NN*D1
  float* xr = xl + (size_t)NN * D1;               // NN*D1, becomes h after agg1
  int* deg  = (int*)(xr + (size_t)NN * D1);       // NN (also cursor)
  int* offs = deg + NN;                           // NN+1
  int* csr  = offs + NN + 1;                      // ET
  float* h2l = xl;                                // alias: xl dead after agg1
  float* h2r = xl + (size_t)NN * C2;

  hipMemsetAsync(deg, 0, NN * sizeof(int), stream);
  k_gemm1<<<dim3(NN / 8, 2), 256, 0, stream>>>(x, W1l, W1r, xl, xr);
  k_hist<<<(ET + 255) / 256, 256, 0, stream>>>(ei, deg);
  k_scan<<<1, 1024, 0, stream>>>(deg, offs);
  k_cursor<<<(NN + 255) / 256, 256, 0, stream>>>(offs, deg);
  k_scatter<<<(ET + 255) / 256, 256, 0, stream>>>(ei, deg, csr);
  k_agg1<<<NN, 256, 0, stream>>>(xl, xr, offs, csr, att1, b1);
  k_gemm2<<<NN / 8, 256, 0, stream>>>(xr, W2l, W2r, h2l, h2r);
  k_agg2<<<NN / 4, 256, 0, stream>>>(h2l, h2r, offs, csr, att2, b2, out);
}

// Round 2
// 475.079 us; speedup vs baseline: 1.4210x; 1.4210x over previous
//
#include <hip/hip_runtime.h>
#include <math.h>

#define NN 50000
#define E0 640000
#define ET 690000   // E0 + NN self loops
#define F1 128
#define D1 256      // 8 heads * 32
#define C2 16
#define NB 196      // ceil(NN/256)

// ---------------- Layer-1 GEMM: xl = x@W1l, xr = x@W1r ----------------
__global__ __launch_bounds__(256) void k_gemm1(
    const float* __restrict__ x, const float* __restrict__ Wl,
    const float* __restrict__ Wr, float* __restrict__ xl, float* __restrict__ xr) {
  const float* W = blockIdx.y ? Wr : Wl;
  float* out = blockIdx.y ? xr : xl;
  __shared__ float lds[F1 * 8];
  const int n0 = blockIdx.x * 8;
  const int t = threadIdx.x;
  for (int idx = t; idx < 8 * F1; idx += 256) {
    int i = idx >> 7, k = idx & 127;
    lds[k * 8 + i] = x[(size_t)(n0 + i) * F1 + k];
  }
  __syncthreads();
  float acc[8];
#pragma unroll
  for (int i = 0; i < 8; ++i) acc[i] = 0.f;
#pragma unroll 4
  for (int k = 0; k < F1; ++k) {
    float w = W[k * D1 + t];
    const float4 a0 = *(const float4*)&lds[k * 8];
    const float4 a1 = *(const float4*)&lds[k * 8 + 4];
    acc[0] += a0.x * w; acc[1] += a0.y * w; acc[2] += a0.z * w; acc[3] += a0.w * w;
    acc[4] += a1.x * w; acc[5] += a1.y * w; acc[6] += a1.z * w; acc[7] += a1.w * w;
  }
#pragma unroll
  for (int i = 0; i < 8; ++i) out[(size_t)(n0 + i) * D1 + t] = acc[i];
}

// ---------------- CSR build ----------------
__global__ void k_hist(const int* __restrict__ ei, int* __restrict__ deg) {
  int e = blockIdx.x * 256 + threadIdx.x;
  if (e >= ET) return;
  int d = (e < E0) ? ei[E0 + e] : (e - E0);
  atomicAdd(&deg[d], 1);
}

// 3-kernel scan: part sums -> top scan -> apply (also inits cursor=deg in place)
__global__ __launch_bounds__(256) void k_scan_part(const int* __restrict__ deg,
                                                   int* __restrict__ part) {
  int i = blockIdx.x * 256 + threadIdx.x;
  int v = (i < NN) ? deg[i] : 0;
  v += __shfl_xor(v, 1);  v += __shfl_xor(v, 2);  v += __shfl_xor(v, 4);
  v += __shfl_xor(v, 8);  v += __shfl_xor(v, 16); v += __shfl_xor(v, 32);
  __shared__ int w[4];
  if ((threadIdx.x & 63) == 0) w[threadIdx.x >> 6] = v;
  __syncthreads();
  if (threadIdx.x == 0) part[blockIdx.x] = w[0] + w[1] + w[2] + w[3];
}

__global__ __launch_bounds__(256) void k_scan_top(int* __restrict__ part,
                                                  int* __restrict__ offs) {
  __shared__ int lds[256];
  int t = threadIdx.x;
  int v = (t < NB) ? part[t] : 0;
  lds[t] = v;
  __syncthreads();
  for (int off = 1; off < 256; off <<= 1) {
    int u = (t >= off) ? lds[t - off] : 0;
    __syncthreads();
    lds[t] += u;
    __syncthreads();
  }
  if (t < NB) part[t] = lds[t] - v;  // exclusive block prefix
  if (t == 255) offs[NN] = lds[255];
}

__global__ __launch_bounds__(256) void k_scan_apply(int* __restrict__ deg,
                                                    const int* __restrict__ part,
                                                    int* __restrict__ offs) {
  __shared__ int lds[256];
  int t = threadIdx.x;
  int i = blockIdx.x * 256 + t;
  int v = (i < NN) ? deg[i] : 0;
  lds[t] = v;
  __syncthreads();
  for (int off = 1; off < 256; off <<= 1) {
    int u = (t >= off) ? lds[t - off] : 0;
    __syncthreads();
    lds[t] += u;
    __syncthreads();
  }
  int excl = lds[t] - v + part[blockIdx.x];
  if (i < NN) { offs[i] = excl; deg[i] = excl; }  // deg becomes cursor
}

__global__ void k_scatter(const int* __restrict__ ei, int* __restrict__ cur,
                          int* __restrict__ csr) {
  int e = blockIdx.x * 256 + threadIdx.x;
  if (e >= ET) return;
  int s, d;
  if (e < E0) { s = ei[e]; d = ei[E0 + e]; } else { s = d = e - E0; }
  int pos = atomicAdd(&cur[d], 1);
  csr[pos] = s;
}

// ---------------- Layer-1 aggregation ----------------
// One wave per node; lane holds 4 feats (head = lane>>3, feats = (lane&7)*4..+3).
// Scores are bounded (|c| < ~10), so no running-max is needed: plain sum of exp.
// Writes ELU(out+b1) in place over xr.
__global__ __launch_bounds__(256) void k_agg1(
    const float* __restrict__ xl, float* __restrict__ xr_h,
    const int* __restrict__ offs, const int* __restrict__ csr,
    const float* __restrict__ att, const float* __restrict__ b1) {
  const int wave = threadIdx.x >> 6;
  const int lane = threadIdx.x & 63;
  const int n = blockIdx.x * 4 + wave;
  const int col = lane * 4;
  const float4 xr4 = *(const float4*)&xr_h[(size_t)n * D1 + col];
  const float4 at4 = *(const float4*)&att[col];
  float l = 0.f;
  float4 acc = make_float4(0.f, 0.f, 0.f, 0.f);
  const int beg = offs[n], fin = offs[n + 1];
  for (int idx = beg; idx < fin; ++idx) {
    const int s = csr[idx];
    const float4 xv = *(const float4*)&xl[(size_t)s * D1 + col];
    float vx = xv.x + xr4.x, vy = xv.y + xr4.y, vz = xv.z + xr4.z, vw = xv.w + xr4.w;
    vx = fmaxf(vx, 0.2f * vx); vy = fmaxf(vy, 0.2f * vy);
    vz = fmaxf(vz, 0.2f * vz); vw = fmaxf(vw, 0.2f * vw);
    float c = vx * at4.x + vy * at4.y + vz * at4.z + vw * at4.w;
    c += __shfl_xor(c, 1);
    c += __shfl_xor(c, 2);
    c += __shfl_xor(c, 4);   // sum over the head's 32 feats (8 lanes x 4)
    const float p = __expf(c);
    l += p;
    acc.x += p * xv.x; acc.y += p * xv.y; acc.z += p * xv.z; acc.w += p * xv.w;
  }
  const float rl = 1.f / (l + 1e-16f);
  const float4 b4 = *(const float4*)&b1[col];
  float4 o;
  o.x = acc.x * rl + b4.x; o.y = acc.y * rl + b4.y;
  o.z = acc.z * rl + b4.z; o.w = acc.w * rl + b4.w;
  o.x = o.x > 0.f ? o.x : expm1f(o.x);
  o.y = o.y > 0.f ? o.y : expm1f(o.y);
  o.z = o.z > 0.f ? o.z : expm1f(o.z);
  o.w = o.w > 0.f ? o.w : expm1f(o.w);
  *(float4*)&xr_h[(size_t)n * D1 + col] = o;
}

// ---------------- Layer-2 GEMM: h2l = h@W2l, h2r = h@W2r ----------------
__global__ __launch_bounds__(256) void k_gemm2(
    const float* __restrict__ h, const float* __restrict__ W2l,
    const float* __restrict__ W2r, float* __restrict__ h2l,
    float* __restrict__ h2r) {
  __shared__ float lds[D1 * 8];
  const int n0 = blockIdx.x * 8;
  const int t = threadIdx.x;
  for (int idx = t; idx < 8 * D1; idx += 256) {
    int i = idx >> 8, k = idx & 255;
    lds[k * 8 + i] = h[(size_t)(n0 + i) * D1 + k];
  }
  __syncthreads();
  const int i = t >> 5, c = t & 31;
  const float* W = (c < 16) ? W2l : W2r;
  float* out = (c < 16) ? h2l : h2r;
  const int cc = c & 15;
  float acc = 0.f;
#pragma unroll 4
  for (int k = 0; k < D1; ++k) acc += lds[k * 8 + i] * W[k * 16 + cc];
  out[(size_t)(n0 + i) * 16 + cc] = acc;
}

// ---------------- Layer-2 aggregation ----------------
__global__ __launch_bounds__(256) void k_agg2(
    const float* __restrict__ h2l, const float* __restrict__ h2r,
    const int* __restrict__ offs, const int* __restrict__ csr,
    const float* __restrict__ att2, const float* __restrict__ b2,
    float* __restrict__ out) {
  const int wave = threadIdx.x >> 6;
  const int lane = threadIdx.x & 63;
  const int n = blockIdx.x * 4 + wave;
  if (n >= NN) return;
  const int c = lane & 15, g = lane >> 4;
  const float xr_v = h2r[(size_t)n * C2 + c];
  const float att_v = att2[c];
  float l = 0.f, acc = 0.f;
  const int beg = offs[n], fin = offs[n + 1];
  for (int idx = beg + g; idx < fin; idx += 4) {
    int s = csr[idx];
    float xlv = h2l[(size_t)s * C2 + c];
    float v = xlv + xr_v;
    v = fmaxf(v, 0.2f * v);
    float sc0 = v * att_v;
    sc0 += __shfl_xor(sc0, 1);
    sc0 += __shfl_xor(sc0, 2);
    sc0 += __shfl_xor(sc0, 4);
    sc0 += __shfl_xor(sc0, 8);           // sum over 16 classes
    float p = __expf(sc0);               // scores bounded, no max needed
    l += p;
    acc += p * xlv;
  }
  // merge the 4 groups (xor 16, 32 stay inside the 64-lane wave)
  l += __shfl_xor(l, 16);   l += __shfl_xor(l, 32);
  acc += __shfl_xor(acc, 16); acc += __shfl_xor(acc, 32);
  float o = acc / (l + 1e-16f) + b2[c];
  o = o > 0.f ? o : 0.01f * o;           // final leaky 0.01
  if (lane < 16) out[(size_t)n * C2 + c] = o;
}

extern "C" void kernel_launch(void* const* d_in, const int* in_sizes, int n_in,
                              void* d_out, int out_size, void* d_ws, size_t ws_size,
                              hipStream_t stream) {
  const float* x    = (const float*)d_in[0];
  const int*   ei   = (const int*)d_in[1];
  const float* W1l  = (const float*)d_in[2];
  const float* W1r  = (const float*)d_in[3];
  const float* att1 = (const float*)d_in[4];
  const float* b1   = (const float*)d_in[5];
  const float* W2l  = (const float*)d_in[6];
  const float* W2r  = (const float*)d_in[7];
  const float* att2 = (const float*)d_in[8];
  const float* b2   = (const float*)d_in[9];
  float* out = (float*)d_out;

  // Workspace layout (~106 MB):
  float* xl = (float*)d_ws;                       // NN*D1
  float* xr = xl + (size_t)NN * D1;               // NN*D1, becomes h after agg1
  int* deg  = (int*)(xr + (size_t)NN * D1);       // NN (becomes cursor)
  int* offs = deg + NN;                           // NN+1
  int* csr  = offs + NN + 1;                      // ET
  int* part = csr + ET;                           // NB
  float* h2l = xl;                                // alias: xl dead after agg1
  float* h2r = xl + (size_t)NN * C2;

  hipMemsetAsync(deg, 0, NN * sizeof(int), stream);
  k_gemm1<<<dim3(NN / 8, 2), 256, 0, stream>>>(x, W1l, W1r, xl, xr);
  k_hist<<<(ET + 255) / 256, 256, 0, stream>>>(ei, deg);
  k_scan_part<<<NB, 256, 0, stream>>>(deg, part);
  k_scan_top<<<1, 256, 0, stream>>>(part, offs);
  k_scan_apply<<<NB, 256, 0, stream>>>(deg, part, offs);
  k_scatter<<<(ET + 255) / 256, 256, 0, stream>>>(ei, deg, csr);
  k_agg1<<<NN / 4, 256, 0, stream>>>(xl, xr, offs, csr, att1, b1);
  k_gemm2<<<NN / 8, 256, 0, stream>>>(xr, W2l, W2r, h2l, h2r);
  k_agg2<<<NN / 4, 256, 0, stream>>>(h2l, h2r, offs, csr, att2, b2, out);
}

// Round 3
// 400.244 us; speedup vs baseline: 1.6867x; 1.1870x over previous
//
#include <hip/hip_runtime.h>
#include <math.h>

#define NN 50000
#define E0 640000
#define ET 690000   // E0 + NN self loops
#define F1 128
#define D1 256      // 8 heads * 32
#define C2 16
#define NB 196      // ceil(NN/256)
#define MPAD 50048  // 391*128, padded node count for MFMA tiles
#define PADK 136    // 128 + 8 bf16 pad (breaks ds_read_b128 bank conflicts)

typedef __attribute__((ext_vector_type(8))) short bf16x8;
typedef __attribute__((ext_vector_type(4))) float f32x4;

__device__ __forceinline__ unsigned short f2bf(float f) {
  union { float f; unsigned u; } c; c.f = f;
  unsigned u = c.u + 0x7FFF + ((c.u >> 16) & 1);  // RNE
  return (unsigned short)(u >> 16);
}

// ---------------- converts ----------------
__global__ __launch_bounds__(256) void k_cvt_x(const float* __restrict__ x,
                                               unsigned short* __restrict__ xb) {
  long long i = (long long)(blockIdx.x * 256 + threadIdx.x) * 4;
  if (i >= (long long)MPAD * F1) return;
  float4 v = (i < (long long)NN * F1) ? *(const float4*)&x[i]
                                      : make_float4(0.f, 0.f, 0.f, 0.f);
  ushort4 o;
  o.x = f2bf(v.x); o.y = f2bf(v.y); o.z = f2bf(v.z); o.w = f2bf(v.w);
  *(ushort4*)&xb[i] = o;
}

// Wt[n][k] bf16, n in [0,512): cols 0..255 from W1l, 256..511 from W1r.
__global__ __launch_bounds__(256) void k_cvt_w(const float* __restrict__ Wl,
                                               const float* __restrict__ Wr,
                                               unsigned short* __restrict__ wt) {
  int tid = blockIdx.x * 256 + threadIdx.x;   // = n*128 + k
  int n = tid >> 7, k = tid & 127;
  float v = (n < 256) ? Wl[k * 256 + n] : Wr[k * 256 + (n - 256)];
  wt[tid] = f2bf(v);
}

// ---------------- Layer-1 GEMM via MFMA ----------------
// C[M=50048, N=512] = xb @ Wt^T.  Block: 128x128 tile, full K=128 in LDS.
// 4 waves in 2x2; each wave 64x64 = 4x4 MFMA tiles, 4 K-steps of 32.
__global__ __launch_bounds__(256) void k_gemm1m(
    const unsigned short* __restrict__ xb, const unsigned short* __restrict__ wt,
    float* __restrict__ xl, float* __restrict__ xr) {
  __shared__ unsigned short Al[128 * PADK];
  __shared__ unsigned short Bl[128 * PADK];
  const int t = threadIdx.x;
  const int m0 = blockIdx.x * 128;
  const int n0 = blockIdx.y * 128;
  {
    const int r = t >> 4;             // 0..15
    const int c = (t & 15) * 8;       // bf16 offset within row
#pragma unroll
    for (int p = 0; p < 8; ++p) {
      const int row = r + p * 16;
      *(float4*)&Al[row * PADK + c] = *(const float4*)&xb[(size_t)(m0 + row) * F1 + c];
      *(float4*)&Bl[row * PADK + c] = *(const float4*)&wt[(size_t)(n0 + row) * F1 + c];
    }
  }
  __syncthreads();
  const int wave = t >> 6, lane = t & 63;
  const int mw = (wave >> 1) * 64, nw = (wave & 1) * 64;
  const int fr = lane & 15, fq = lane >> 4;
  f32x4 acc[4][4] = {};
#pragma unroll
  for (int ks = 0; ks < 4; ++ks) {
    const int ko = ks * 32 + fq * 8;
    bf16x8 a[4], b[4];
#pragma unroll
    for (int i = 0; i < 4; ++i)
      a[i] = *(const bf16x8*)&Al[(mw + i * 16 + fr) * PADK + ko];
#pragma unroll
    for (int j = 0; j < 4; ++j)
      b[j] = *(const bf16x8*)&Bl[(nw + j * 16 + fr) * PADK + ko];
#pragma unroll
    for (int i = 0; i < 4; ++i)
#pragma unroll
      for (int j = 0; j < 4; ++j)
        acc[i][j] = __builtin_amdgcn_mfma_f32_16x16x32_bf16(a[i], b[j], acc[i][j], 0, 0, 0);
  }
  float* outp = (n0 < 256) ? xl : xr;
  const int cb = (n0 & 255) + nw + fr;
#pragma unroll
  for (int i = 0; i < 4; ++i) {
    const int gm0 = m0 + mw + i * 16 + fq * 4;
#pragma unroll
    for (int j = 0; j < 4; ++j) {
#pragma unroll
      for (int r = 0; r < 4; ++r) {
        const int gm = gm0 + r;
        if (gm < NN) outp[(size_t)gm * D1 + cb + j * 16] = acc[i][j][r];
      }
    }
  }
}

// ---------------- CSR build ----------------
__global__ void k_hist(const int* __restrict__ ei, int* __restrict__ deg) {
  int e = blockIdx.x * 256 + threadIdx.x;
  if (e >= ET) return;
  int d = (e < E0) ? ei[E0 + e] : (e - E0);
  atomicAdd(&deg[d], 1);
}

__global__ __launch_bounds__(256) void k_scan_part(const int* __restrict__ deg,
                                                   int* __restrict__ part) {
  int i = blockIdx.x * 256 + threadIdx.x;
  int v = (i < NN) ? deg[i] : 0;
  v += __shfl_xor(v, 1);  v += __shfl_xor(v, 2);  v += __shfl_xor(v, 4);
  v += __shfl_xor(v, 8);  v += __shfl_xor(v, 16); v += __shfl_xor(v, 32);
  __shared__ int w[4];
  if ((threadIdx.x & 63) == 0) w[threadIdx.x >> 6] = v;
  __syncthreads();
  if (threadIdx.x == 0) part[blockIdx.x] = w[0] + w[1] + w[2] + w[3];
}

__global__ __launch_bounds__(256) void k_scan_top(int* __restrict__ part,
                                                  int* __restrict__ offs) {
  __shared__ int lds[256];
  int t = threadIdx.x;
  int v = (t < NB) ? part[t] : 0;
  lds[t] = v;
  __syncthreads();
  for (int off = 1; off < 256; off <<= 1) {
    int u = (t >= off) ? lds[t - off] : 0;
    __syncthreads();
    lds[t] += u;
    __syncthreads();
  }
  if (t < NB) part[t] = lds[t] - v;
  if (t == 255) offs[NN] = lds[255];
}

__global__ __launch_bounds__(256) void k_scan_apply(int* __restrict__ deg,
                                                    const int* __restrict__ part,
                                                    int* __restrict__ offs) {
  __shared__ int lds[256];
  int t = threadIdx.x;
  int i = blockIdx.x * 256 + t;
  int v = (i < NN) ? deg[i] : 0;
  lds[t] = v;
  __syncthreads();
  for (int off = 1; off < 256; off <<= 1) {
    int u = (t >= off) ? lds[t - off] : 0;
    __syncthreads();
    lds[t] += u;
    __syncthreads();
  }
  int excl = lds[t] - v + part[blockIdx.x];
  if (i < NN) { offs[i] = excl; deg[i] = excl; }  // deg becomes cursor
}

__global__ void k_scatter(const int* __restrict__ ei, int* __restrict__ cur,
                          int* __restrict__ csr) {
  int e = blockIdx.x * 256 + threadIdx.x;
  if (e >= ET) return;
  int s, d;
  if (e < E0) { s = ei[e]; d = ei[E0 + e]; } else { s = d = e - E0; }
  int pos = atomicAdd(&cur[d], 1);
  csr[pos] = s;
}

// ---------------- Layer-1 aggregation ----------------
// One wave per node; lane holds 4 feats. Scores bounded -> no running max.
__global__ __launch_bounds__(256) void k_agg1(
    const float* __restrict__ xl, float* __restrict__ xr_h,
    const int* __restrict__ offs, const int* __restrict__ csr,
    const float* __restrict__ att, const float* __restrict__ b1) {
  const int wave = threadIdx.x >> 6;
  const int lane = threadIdx.x & 63;
  const int n = blockIdx.x * 4 + wave;
  const int col = lane * 4;
  const float4 xr4 = *(const float4*)&xr_h[(size_t)n * D1 + col];
  const float4 at4 = *(const float4*)&att[col];
  float l = 0.f;
  float4 acc = make_float4(0.f, 0.f, 0.f, 0.f);
  const int beg = offs[n], fin = offs[n + 1];
  for (int idx = beg; idx < fin; ++idx) {
    const int s = csr[idx];
    const float4 xv = *(const float4*)&xl[(size_t)s * D1 + col];
    float vx = xv.x + xr4.x, vy = xv.y + xr4.y, vz = xv.z + xr4.z, vw = xv.w + xr4.w;
    vx = fmaxf(vx, 0.2f * vx); vy = fmaxf(vy, 0.2f * vy);
    vz = fmaxf(vz, 0.2f * vz); vw = fmaxf(vw, 0.2f * vw);
    float c = vx * at4.x + vy * at4.y + vz * at4.z + vw * at4.w;
    c += __shfl_xor(c, 1);
    c += __shfl_xor(c, 2);
    c += __shfl_xor(c, 4);
    const float p = __expf(c);
    l += p;
    acc.x += p * xv.x; acc.y += p * xv.y; acc.z += p * xv.z; acc.w += p * xv.w;
  }
  const float rl = 1.f / (l + 1e-16f);
  const float4 b4 = *(const float4*)&b1[col];
  float4 o;
  o.x = acc.x * rl + b4.x; o.y = acc.y * rl + b4.y;
  o.z = acc.z * rl + b4.z; o.w = acc.w * rl + b4.w;
  o.x = o.x > 0.f ? o.x : expm1f(o.x);
  o.y = o.y > 0.f ? o.y : expm1f(o.y);
  o.z = o.z > 0.f ? o.z : expm1f(o.z);
  o.w = o.w > 0.f ? o.w : expm1f(o.w);
  *(float4*)&xr_h[(size_t)n * D1 + col] = o;
}

// ---------------- Layer-2 GEMM ----------------
__global__ __launch_bounds__(256) void k_gemm2(
    const float* __restrict__ h, const float* __restrict__ W2l,
    const float* __restrict__ W2r, float* __restrict__ h2l,
    float* __restrict__ h2r) {
  __shared__ float lds[D1 * 8];
  const int n0 = blockIdx.x * 8;
  const int t = threadIdx.x;
  for (int idx = t; idx < 8 * D1; idx += 256) {
    int i = idx >> 8, k = idx & 255;
    lds[k * 8 + i] = h[(size_t)(n0 + i) * D1 + k];
  }
  __syncthreads();
  const int i = t >> 5, c = t & 31;
  const float* W = (c < 16) ? W2l : W2r;
  float* out = (c < 16) ? h2l : h2r;
  const int cc = c & 15;
  float acc = 0.f;
#pragma unroll 4
  for (int k = 0; k < D1; ++k) acc += lds[k * 8 + i] * W[k * 16 + cc];
  out[(size_t)(n0 + i) * 16 + cc] = acc;
}

// ---------------- Layer-2 aggregation ----------------
__global__ __launch_bounds__(256) void k_agg2(
    const float* __restrict__ h2l, const float* __restrict__ h2r,
    const int* __restrict__ offs, const int* __restrict__ csr,
    const float* __restrict__ att2, const float* __restrict__ b2,
    float* __restrict__ out) {
  const int wave = threadIdx.x >> 6;
  const int lane = threadIdx.x & 63;
  const int n = blockIdx.x * 4 + wave;
  if (n >= NN) return;
  const int c = lane & 15, g = lane >> 4;
  const float xr_v = h2r[(size_t)n * C2 + c];
  const float att_v = att2[c];
  float l = 0.f, acc = 0.f;
  const int beg = offs[n], fin = offs[n + 1];
  for (int idx = beg + g; idx < fin; idx += 4) {
    int s = csr[idx];
    float xlv = h2l[(size_t)s * C2 + c];
    float v = xlv + xr_v;
    v = fmaxf(v, 0.2f * v);
    float sc0 = v * att_v;
    sc0 += __shfl_xor(sc0, 1);
    sc0 += __shfl_xor(sc0, 2);
    sc0 += __shfl_xor(sc0, 4);
    sc0 += __shfl_xor(sc0, 8);
    float p = __expf(sc0);
    l += p;
    acc += p * xlv;
  }
  l += __shfl_xor(l, 16);   l += __shfl_xor(l, 32);
  acc += __shfl_xor(acc, 16); acc += __shfl_xor(acc, 32);
  float o = acc / (l + 1e-16f) + b2[c];
  o = o > 0.f ? o : 0.01f * o;
  if (lane < 16) out[(size_t)n * C2 + c] = o;
}

extern "C" void kernel_launch(void* const* d_in, const int* in_sizes, int n_in,
                              void* d_out, int out_size, void* d_ws, size_t ws_size,
                              hipStream_t stream) {
  const float* x    = (const float*)d_in[0];
  const int*   ei   = (const int*)d_in[1];
  const float* W1l  = (const float*)d_in[2];
  const float* W1r  = (const float*)d_in[3];
  const float* att1 = (const float*)d_in[4];
  const float* b1   = (const float*)d_in[5];
  const float* W2l  = (const float*)d_in[6];
  const float* W2r  = (const float*)d_in[7];
  const float* att2 = (const float*)d_in[8];
  const float* b2   = (const float*)d_in[9];
  float* out = (float*)d_out;

  // Workspace layout (~119 MB):
  float* xl = (float*)d_ws;                       // NN*D1
  float* xr = xl + (size_t)NN * D1;               // NN*D1, becomes h after agg1
  int* deg  = (int*)(xr + (size_t)NN * D1);       // NN (becomes cursor)
  int* offs = deg + NN;                           // NN+1
  int* csr  = offs + NN + 1;                      // ET
  int* part = csr + ET;                           // NB
  unsigned short* xb = (unsigned short*)(part + NB);  // MPAD*F1 bf16
  unsigned short* wt = xb + (size_t)MPAD * F1;        // 512*128 bf16
  float* h2l = xl;                                // alias: xl dead after agg1
  float* h2r = xl + (size_t)NN * C2;

  hipMemsetAsync(deg, 0, NN * sizeof(int), stream);
  k_cvt_x<<<(MPAD * F1 / 4 + 255) / 256, 256, 0, stream>>>(x, xb);
  k_cvt_w<<<512 * F1 / 256, 256, 0, stream>>>(W1l, W1r, wt);
  k_gemm1m<<<dim3(MPAD / 128, 4), 256, 0, stream>>>(xb, wt, xl, xr);
  k_hist<<<(ET + 255) / 256, 256, 0, stream>>>(ei, deg);
  k_scan_part<<<NB, 256, 0, stream>>>(deg, part);
  k_scan_top<<<1, 256, 0, stream>>>(part, offs);
  k_scan_apply<<<NB, 256, 0, stream>>>(deg, part, offs);
  k_scatter<<<(ET + 255) / 256, 256, 0, stream>>>(ei, deg, csr);
  k_agg1<<<NN / 4, 256, 0, stream>>>(xl, xr, offs, csr, att1, b1);
  k_gemm2<<<NN / 8, 256, 0, stream>>>(xr, W2l, W2r, h2l, h2r);
  k_agg2<<<NN / 4, 256, 0, stream>>>(h2l, h2r, offs, csr, att2, b2, out);
}

// Round 4
// 341.903 us; speedup vs baseline: 1.9745x; 1.1706x over previous
//
#include <hip/hip_runtime.h>
#include <math.h>

#define NN 50000
#define E0 640000
#define ET 690000   // E0 + NN self loops
#define F1 128
#define D1 256      // 8 heads * 32
#define C2 16
#define NB 196      // ceil(NN/256)
#define MPAD 50048  // 391*128, padded node count for MFMA tiles
#define PADK 136    // 128 + 8 bf16 pad (breaks ds_read_b128 bank conflicts)

typedef __attribute__((ext_vector_type(8))) short bf16x8;
typedef __attribute__((ext_vector_type(4))) float f32x4;

__device__ __forceinline__ unsigned short f2bf(float f) {
  union { float f; unsigned u; } c; c.f = f;
  unsigned u = c.u + 0x7FFF + ((c.u >> 16) & 1);  // RNE
  return (unsigned short)(u >> 16);
}

// ---------------- converts ----------------
__global__ __launch_bounds__(256) void k_cvt_x(const float* __restrict__ x,
                                               unsigned short* __restrict__ xb) {
  long long i = (long long)(blockIdx.x * 256 + threadIdx.x) * 4;
  if (i >= (long long)MPAD * F1) return;
  float4 v = (i < (long long)NN * F1) ? *(const float4*)&x[i]
                                      : make_float4(0.f, 0.f, 0.f, 0.f);
  ushort4 o;
  o.x = f2bf(v.x); o.y = f2bf(v.y); o.z = f2bf(v.z); o.w = f2bf(v.w);
  *(ushort4*)&xb[i] = o;
}

// Wt[n][k] bf16, n in [0,512): cols 0..255 from W1l, 256..511 from W1r.
__global__ __launch_bounds__(256) void k_cvt_w(const float* __restrict__ Wl,
                                               const float* __restrict__ Wr,
                                               unsigned short* __restrict__ wt) {
  int tid = blockIdx.x * 256 + threadIdx.x;   // = n*128 + k
  int n = tid >> 7, k = tid & 127;
  float v = (n < 256) ? Wl[k * 256 + n] : Wr[k * 256 + (n - 256)];
  wt[tid] = f2bf(v);
}

// ---------------- Layer-1 GEMM via MFMA ----------------
// C[M=50048, N=512] = xb @ Wt^T. xl half stored as bf16, xr half fp32.
__global__ __launch_bounds__(256) void k_gemm1m(
    const unsigned short* __restrict__ xb, const unsigned short* __restrict__ wt,
    unsigned short* __restrict__ xlb, float* __restrict__ xr) {
  __shared__ unsigned short Al[128 * PADK];
  __shared__ unsigned short Bl[128 * PADK];
  const int t = threadIdx.x;
  const int m0 = blockIdx.x * 128;
  const int n0 = blockIdx.y * 128;
  {
    const int r = t >> 4;             // 0..15
    const int c = (t & 15) * 8;       // bf16 offset within row
#pragma unroll
    for (int p = 0; p < 8; ++p) {
      const int row = r + p * 16;
      *(float4*)&Al[row * PADK + c] = *(const float4*)&xb[(size_t)(m0 + row) * F1 + c];
      *(float4*)&Bl[row * PADK + c] = *(const float4*)&wt[(size_t)(n0 + row) * F1 + c];
    }
  }
  __syncthreads();
  const int wave = t >> 6, lane = t & 63;
  const int mw = (wave >> 1) * 64, nw = (wave & 1) * 64;
  const int fr = lane & 15, fq = lane >> 4;
  f32x4 acc[4][4] = {};
#pragma unroll
  for (int ks = 0; ks < 4; ++ks) {
    const int ko = ks * 32 + fq * 8;
    bf16x8 a[4], b[4];
#pragma unroll
    for (int i = 0; i < 4; ++i)
      a[i] = *(const bf16x8*)&Al[(mw + i * 16 + fr) * PADK + ko];
#pragma unroll
    for (int j = 0; j < 4; ++j)
      b[j] = *(const bf16x8*)&Bl[(nw + j * 16 + fr) * PADK + ko];
#pragma unroll
    for (int i = 0; i < 4; ++i)
#pragma unroll
      for (int j = 0; j < 4; ++j)
        acc[i][j] = __builtin_amdgcn_mfma_f32_16x16x32_bf16(a[i], b[j], acc[i][j], 0, 0, 0);
  }
  if (n0 < 256) {  // xl half -> bf16
    const int cb = n0 + nw + fr;
#pragma unroll
    for (int i = 0; i < 4; ++i) {
      const int gm0 = m0 + mw + i * 16 + fq * 4;
#pragma unroll
      for (int j = 0; j < 4; ++j)
#pragma unroll
        for (int r = 0; r < 4; ++r) {
          const int gm = gm0 + r;
          if (gm < NN) xlb[(size_t)gm * D1 + cb + j * 16] = f2bf(acc[i][j][r]);
        }
    }
  } else {         // xr half -> fp32
    const int cb = (n0 - 256) + nw + fr;
#pragma unroll
    for (int i = 0; i < 4; ++i) {
      const int gm0 = m0 + mw + i * 16 + fq * 4;
#pragma unroll
      for (int j = 0; j < 4; ++j)
#pragma unroll
        for (int r = 0; r < 4; ++r) {
          const int gm = gm0 + r;
          if (gm < NN) xr[(size_t)gm * D1 + cb + j * 16] = acc[i][j][r];
        }
    }
  }
}

// ---------------- CSR build ----------------
__global__ void k_hist(const int* __restrict__ ei, int* __restrict__ deg) {
  int e = blockIdx.x * 256 + threadIdx.x;
  if (e >= ET) return;
  int d = (e < E0) ? ei[E0 + e] : (e - E0);
  atomicAdd(&deg[d], 1);
}

__global__ __launch_bounds__(256) void k_scan_part(const int* __restrict__ deg,
                                                   int* __restrict__ part) {
  int i = blockIdx.x * 256 + threadIdx.x;
  int v = (i < NN) ? deg[i] : 0;
  v += __shfl_xor(v, 1);  v += __shfl_xor(v, 2);  v += __shfl_xor(v, 4);
  v += __shfl_xor(v, 8);  v += __shfl_xor(v, 16); v += __shfl_xor(v, 32);
  __shared__ int w[4];
  if ((threadIdx.x & 63) == 0) w[threadIdx.x >> 6] = v;
  __syncthreads();
  if (threadIdx.x == 0) part[blockIdx.x] = w[0] + w[1] + w[2] + w[3];
}

__global__ __launch_bounds__(256) void k_scan_top(int* __restrict__ part,
                                                  int* __restrict__ offs) {
  __shared__ int lds[256];
  int t = threadIdx.x;
  int v = (t < NB) ? part[t] : 0;
  lds[t] = v;
  __syncthreads();
  for (int off = 1; off < 256; off <<= 1) {
    int u = (t >= off) ? lds[t - off] : 0;
    __syncthreads();
    lds[t] += u;
    __syncthreads();
  }
  if (t < NB) part[t] = lds[t] - v;
  if (t == 255) offs[NN] = lds[255];
}

__global__ __launch_bounds__(256) void k_scan_apply(int* __restrict__ deg,
                                                    const int* __restrict__ part,
                                                    int* __restrict__ offs) {
  __shared__ int lds[256];
  int t = threadIdx.x;
  int i = blockIdx.x * 256 + t;
  int v = (i < NN) ? deg[i] : 0;
  lds[t] = v;
  __syncthreads();
  for (int off = 1; off < 256; off <<= 1) {
    int u = (t >= off) ? lds[t - off] : 0;
    __syncthreads();
    lds[t] += u;
    __syncthreads();
  }
  int excl = lds[t] - v + part[blockIdx.x];
  if (i < NN) { offs[i] = excl; deg[i] = excl; }  // deg becomes cursor
}

__global__ void k_scatter(const int* __restrict__ ei, int* __restrict__ cur,
                          int* __restrict__ csr) {
  int e = blockIdx.x * 256 + threadIdx.x;
  if (e >= ET) return;
  int s, d;
  if (e < E0) { s = ei[e]; d = ei[E0 + e]; } else { s = d = e - E0; }
  int pos = atomicAdd(&cur[d], 1);
  csr[pos] = s;
}

// ---------------- Layer-1 aggregation ----------------
// One wave per node. Lane holds 8 feats (16B bf16 load); half-waves process
// alternating edges (2/wave), 2x unroll -> 4 gathers in flight. Scores
// bounded -> plain sum of exp. Writes ELU(out+b1) in place over xr.
__global__ __launch_bounds__(256) void k_agg1(
    const unsigned short* __restrict__ xlb, float* __restrict__ xr_h,
    const int* __restrict__ offs, const int* __restrict__ csr,
    const float* __restrict__ att, const float* __restrict__ b1) {
  const int wave = threadIdx.x >> 6;
  const int lane = threadIdx.x & 63;
  const int n = blockIdx.x * 4 + wave;
  const int half = lane >> 5;
  const int sub = lane & 31;
  const int col = sub * 8;
  float xr8[8], at8[8];
  *(float4*)&xr8[0] = *(const float4*)&xr_h[(size_t)n * D1 + col];
  *(float4*)&xr8[4] = *(const float4*)&xr_h[(size_t)n * D1 + col + 4];
  *(float4*)&at8[0] = *(const float4*)&att[col];
  *(float4*)&at8[4] = *(const float4*)&att[col + 4];
  float l = 0.f;
  float acc[8] = {0.f, 0.f, 0.f, 0.f, 0.f, 0.f, 0.f, 0.f};
  const int beg = offs[n], fin = offs[n + 1];

  auto body = [&](uint4 w) {
    float xf[8];
    xf[0] = __uint_as_float(w.x << 16);  xf[1] = __uint_as_float(w.x & 0xffff0000u);
    xf[2] = __uint_as_float(w.y << 16);  xf[3] = __uint_as_float(w.y & 0xffff0000u);
    xf[4] = __uint_as_float(w.z << 16);  xf[5] = __uint_as_float(w.z & 0xffff0000u);
    xf[6] = __uint_as_float(w.w << 16);  xf[7] = __uint_as_float(w.w & 0xffff0000u);
    float c = 0.f;
#pragma unroll
    for (int k = 0; k < 8; ++k) {
      float v = xf[k] + xr8[k];
      v = fmaxf(v, 0.2f * v);
      c = fmaf(v, at8[k], c);
    }
    c += __shfl_xor(c, 1);
    c += __shfl_xor(c, 2);   // sum over the head's 4 lanes (32 feats)
    const float p = __expf(c);
    l += p;
#pragma unroll
    for (int k = 0; k < 8; ++k) acc[k] = fmaf(p, xf[k], acc[k]);
  };

  int idx = beg + half;
  for (; idx + 2 < fin; idx += 4) {
    const int s0 = csr[idx], s1 = csr[idx + 2];
    const uint4 w0 = *(const uint4*)&xlb[(size_t)s0 * D1 + col];
    const uint4 w1 = *(const uint4*)&xlb[(size_t)s1 * D1 + col];
    body(w0);
    body(w1);
  }
  for (; idx < fin; idx += 2) {
    const int s0 = csr[idx];
    const uint4 w0 = *(const uint4*)&xlb[(size_t)s0 * D1 + col];
    body(w0);
  }
  // merge halves (lane i and i+32 hold the same feats/head)
  l += __shfl_xor(l, 32);
#pragma unroll
  for (int k = 0; k < 8; ++k) acc[k] += __shfl_xor(acc[k], 32);
  if (half == 0) {
    const float rl = 1.f / (l + 1e-16f);
    float b8[8], o[8];
    *(float4*)&b8[0] = *(const float4*)&b1[col];
    *(float4*)&b8[4] = *(const float4*)&b1[col + 4];
#pragma unroll
    for (int k = 0; k < 8; ++k) {
      o[k] = acc[k] * rl + b8[k];
      o[k] = o[k] > 0.f ? o[k] : expm1f(o[k]);
    }
    *(float4*)&xr_h[(size_t)n * D1 + col] = *(float4*)&o[0];
    *(float4*)&xr_h[(size_t)n * D1 + col + 4] = *(float4*)&o[4];
  }
}

// ---------------- Layer-2 GEMM ----------------
__global__ __launch_bounds__(256) void k_gemm2(
    const float* __restrict__ h, const float* __restrict__ W2l,
    const float* __restrict__ W2r, float* __restrict__ h2l,
    float* __restrict__ h2r) {
  __shared__ float lds[D1 * 8];
  const int n0 = blockIdx.x * 8;
  const int t = threadIdx.x;
  for (int idx = t; idx < 8 * D1; idx += 256) {
    int i = idx >> 8, k = idx & 255;
    lds[k * 8 + i] = h[(size_t)(n0 + i) * D1 + k];
  }
  __syncthreads();
  const int i = t >> 5, c = t & 31;
  const float* W = (c < 16) ? W2l : W2r;
  float* out = (c < 16) ? h2l : h2r;
  const int cc = c & 15;
  float acc = 0.f;
#pragma unroll 4
  for (int k = 0; k < D1; ++k) acc += lds[k * 8 + i] * W[k * 16 + cc];
  out[(size_t)(n0 + i) * 16 + cc] = acc;
}

// ---------------- Layer-2 aggregation ----------------
__global__ __launch_bounds__(256) void k_agg2(
    const float* __restrict__ h2l, const float* __restrict__ h2r,
    const int* __restrict__ offs, const int* __restrict__ csr,
    const float* __restrict__ att2, const float* __restrict__ b2,
    float* __restrict__ out) {
  const int wave = threadIdx.x >> 6;
  const int lane = threadIdx.x & 63;
  const int n = blockIdx.x * 4 + wave;
  if (n >= NN) return;
  const int c = lane & 15, g = lane >> 4;
  const float xr_v = h2r[(size_t)n * C2 + c];
  const float att_v = att2[c];
  float l = 0.f, acc = 0.f;
  const int beg = offs[n], fin = offs[n + 1];
  for (int idx = beg + g; idx < fin; idx += 4) {
    int s = csr[idx];
    float xlv = h2l[(size_t)s * C2 + c];
    float v = xlv + xr_v;
    v = fmaxf(v, 0.2f * v);
    float sc0 = v * att_v;
    sc0 += __shfl_xor(sc0, 1);
    sc0 += __shfl_xor(sc0, 2);
    sc0 += __shfl_xor(sc0, 4);
    sc0 += __shfl_xor(sc0, 8);
    float p = __expf(sc0);
    l += p;
    acc += p * xlv;
  }
  l += __shfl_xor(l, 16);   l += __shfl_xor(l, 32);
  acc += __shfl_xor(acc, 16); acc += __shfl_xor(acc, 32);
  float o = acc / (l + 1e-16f) + b2[c];
  o = o > 0.f ? o : 0.01f * o;
  if (lane < 16) out[(size_t)n * C2 + c] = o;
}

extern "C" void kernel_launch(void* const* d_in, const int* in_sizes, int n_in,
                              void* d_out, int out_size, void* d_ws, size_t ws_size,
                              hipStream_t stream) {
  const float* x    = (const float*)d_in[0];
  const int*   ei   = (const int*)d_in[1];
  const float* W1l  = (const float*)d_in[2];
  const float* W1r  = (const float*)d_in[3];
  const float* att1 = (const float*)d_in[4];
  const float* b1   = (const float*)d_in[5];
  const float* W2l  = (const float*)d_in[6];
  const float* W2r  = (const float*)d_in[7];
  const float* att2 = (const float*)d_in[8];
  const float* b2   = (const float*)d_in[9];
  float* out = (float*)d_out;

  // Workspace layout (~94 MB):
  unsigned short* xlb = (unsigned short*)d_ws;    // NN*D1 bf16 (25.6 MB)
  float* xr = (float*)(xlb + (size_t)NN * D1);    // NN*D1 f32, becomes h
  int* deg  = (int*)(xr + (size_t)NN * D1);       // NN (becomes cursor)
  int* offs = deg + NN;                           // NN+1
  int* csr  = offs + NN + 1;                      // ET
  int* part = csr + ET;                           // NB
  unsigned short* xb = (unsigned short*)(part + NB);  // MPAD*F1 bf16
  unsigned short* wt = xb + (size_t)MPAD * F1;        // 512*128 bf16
  float* h2l = (float*)xlb;                       // alias: xlb dead after agg1
  float* h2r = h2l + (size_t)NN * C2;

  hipMemsetAsync(deg, 0, NN * sizeof(int), stream);
  k_cvt_x<<<(MPAD * F1 / 4 + 255) / 256, 256, 0, stream>>>(x, xb);
  k_cvt_w<<<512 * F1 / 256, 256, 0, stream>>>(W1l, W1r, wt);
  k_gemm1m<<<dim3(MPAD / 128, 4), 256, 0, stream>>>(xb, wt, xlb, xr);
  k_hist<<<(ET + 255) / 256, 256, 0, stream>>>(ei, deg);
  k_scan_part<<<NB, 256, 0, stream>>>(deg, part);
  k_scan_top<<<1, 256, 0, stream>>>(part, offs);
  k_scan_apply<<<NB, 256, 0, stream>>>(deg, part, offs);
  k_scatter<<<(ET + 255) / 256, 256, 0, stream>>>(ei, deg, csr);
  k_agg1<<<NN / 4, 256, 0, stream>>>(xlb, xr, offs, csr, att1, b1);
  k_gemm2<<<NN / 8, 256, 0, stream>>>(xr, W2l, W2r, h2l, h2r);
  k_agg2<<<NN / 4, 256, 0, stream>>>(h2l, h2r, offs, csr, att2, b2, out);
}

// Round 5
// 339.391 us; speedup vs baseline: 1.9891x; 1.0074x over previous
//
#include <hip/hip_runtime.h>
#include <math.h>

#define NN 50000
#define E0 640000
#define ET 690000   // E0 + NN self loops
#define F1 128
#define D1 256      // 8 heads * 32
#define C2 16
#define NB 196      // ceil(NN/256)
#define MPAD 50048  // 391*128, padded node count for MFMA tiles
#define PADK 136    // 128 + 8 bf16 pad (breaks ds_read_b128 bank conflicts)

typedef __attribute__((ext_vector_type(8))) short bf16x8;
typedef __attribute__((ext_vector_type(4))) float f32x4;

__device__ __forceinline__ unsigned short f2bf(float f) {
  union { float f; unsigned u; } c; c.f = f;
  unsigned u = c.u + 0x7FFF + ((c.u >> 16) & 1);  // RNE
  return (unsigned short)(u >> 16);
}

// ---------------- converts ----------------
__global__ __launch_bounds__(256) void k_cvt_x(const float* __restrict__ x,
                                               unsigned short* __restrict__ xb) {
  long long i = (long long)(blockIdx.x * 256 + threadIdx.x) * 4;
  if (i >= (long long)MPAD * F1) return;
  float4 v = (i < (long long)NN * F1) ? *(const float4*)&x[i]
                                      : make_float4(0.f, 0.f, 0.f, 0.f);
  ushort4 o;
  o.x = f2bf(v.x); o.y = f2bf(v.y); o.z = f2bf(v.z); o.w = f2bf(v.w);
  *(ushort4*)&xb[i] = o;
}

// Wt[n][k] bf16, n in [0,512): cols 0..255 from W1l, 256..511 from W1r.
__global__ __launch_bounds__(256) void k_cvt_w(const float* __restrict__ Wl,
                                               const float* __restrict__ Wr,
                                               unsigned short* __restrict__ wt) {
  int tid = blockIdx.x * 256 + threadIdx.x;   // = n*128 + k
  int n = tid >> 7, k = tid & 127;
  float v = (n < 256) ? Wl[k * 256 + n] : Wr[k * 256 + (n - 256)];
  wt[tid] = f2bf(v);
}

// ---------------- Layer-1 GEMM via MFMA ----------------
// C[M=50048, N=512] = xb @ Wt^T. xl half stored as bf16, xr half fp32.
__global__ __launch_bounds__(256) void k_gemm1m(
    const unsigned short* __restrict__ xb, const unsigned short* __restrict__ wt,
    unsigned short* __restrict__ xlb, float* __restrict__ xr) {
  __shared__ unsigned short Al[128 * PADK];
  __shared__ unsigned short Bl[128 * PADK];
  const int t = threadIdx.x;
  const int m0 = blockIdx.x * 128;
  const int n0 = blockIdx.y * 128;
  {
    const int r = t >> 4;             // 0..15
    const int c = (t & 15) * 8;       // bf16 offset within row
#pragma unroll
    for (int p = 0; p < 8; ++p) {
      const int row = r + p * 16;
      *(float4*)&Al[row * PADK + c] = *(const float4*)&xb[(size_t)(m0 + row) * F1 + c];
      *(float4*)&Bl[row * PADK + c] = *(const float4*)&wt[(size_t)(n0 + row) * F1 + c];
    }
  }
  __syncthreads();
  const int wave = t >> 6, lane = t & 63;
  const int mw = (wave >> 1) * 64, nw = (wave & 1) * 64;
  const int fr = lane & 15, fq = lane >> 4;
  f32x4 acc[4][4] = {};
#pragma unroll
  for (int ks = 0; ks < 4; ++ks) {
    const int ko = ks * 32 + fq * 8;
    bf16x8 a[4], b[4];
#pragma unroll
    for (int i = 0; i < 4; ++i)
      a[i] = *(const bf16x8*)&Al[(mw + i * 16 + fr) * PADK + ko];
#pragma unroll
    for (int j = 0; j < 4; ++j)
      b[j] = *(const bf16x8*)&Bl[(nw + j * 16 + fr) * PADK + ko];
#pragma unroll
    for (int i = 0; i < 4; ++i)
#pragma unroll
      for (int j = 0; j < 4; ++j)
        acc[i][j] = __builtin_amdgcn_mfma_f32_16x16x32_bf16(a[i], b[j], acc[i][j], 0, 0, 0);
  }
  if (n0 < 256) {  // xl half -> bf16
    const int cb = n0 + nw + fr;
#pragma unroll
    for (int i = 0; i < 4; ++i) {
      const int gm0 = m0 + mw + i * 16 + fq * 4;
#pragma unroll
      for (int j = 0; j < 4; ++j)
#pragma unroll
        for (int r = 0; r < 4; ++r) {
          const int gm = gm0 + r;
          if (gm < NN) xlb[(size_t)gm * D1 + cb + j * 16] = f2bf(acc[i][j][r]);
        }
    }
  } else {         // xr half -> fp32
    const int cb = (n0 - 256) + nw + fr;
#pragma unroll
    for (int i = 0; i < 4; ++i) {
      const int gm0 = m0 + mw + i * 16 + fq * 4;
#pragma unroll
      for (int j = 0; j < 4; ++j)
#pragma unroll
        for (int r = 0; r < 4; ++r) {
          const int gm = gm0 + r;
          if (gm < NN) xr[(size_t)gm * D1 + cb + j * 16] = acc[i][j][r];
        }
    }
  }
}

// ---------------- CSR build ----------------
__global__ void k_hist(const int* __restrict__ ei, int* __restrict__ deg) {
  int e = blockIdx.x * 256 + threadIdx.x;
  if (e >= ET) return;
  int d = (e < E0) ? ei[E0 + e] : (e - E0);
  atomicAdd(&deg[d], 1);
}

__global__ __launch_bounds__(256) void k_scan_part(const int* __restrict__ deg,
                                                   int* __restrict__ part) {
  int i = blockIdx.x * 256 + threadIdx.x;
  int v = (i < NN) ? deg[i] : 0;
  v += __shfl_xor(v, 1);  v += __shfl_xor(v, 2);  v += __shfl_xor(v, 4);
  v += __shfl_xor(v, 8);  v += __shfl_xor(v, 16); v += __shfl_xor(v, 32);
  __shared__ int w[4];
  if ((threadIdx.x & 63) == 0) w[threadIdx.x >> 6] = v;
  __syncthreads();
  if (threadIdx.x == 0) part[blockIdx.x] = w[0] + w[1] + w[2] + w[3];
}

__global__ __launch_bounds__(256) void k_scan_top(int* __restrict__ part,
                                                  int* __restrict__ offs) {
  __shared__ int lds[256];
  int t = threadIdx.x;
  int v = (t < NB) ? part[t] : 0;
  lds[t] = v;
  __syncthreads();
  for (int off = 1; off < 256; off <<= 1) {
    int u = (t >= off) ? lds[t - off] : 0;
    __syncthreads();
    lds[t] += u;
    __syncthreads();
  }
  if (t < NB) part[t] = lds[t] - v;
  if (t == 255) offs[NN] = lds[255];
}

__global__ __launch_bounds__(256) void k_scan_apply(int* __restrict__ deg,
                                                    const int* __restrict__ part,
                                                    int* __restrict__ offs) {
  __shared__ int lds[256];
  int t = threadIdx.x;
  int i = blockIdx.x * 256 + t;
  int v = (i < NN) ? deg[i] : 0;
  lds[t] = v;
  __syncthreads();
  for (int off = 1; off < 256; off <<= 1) {
    int u = (t >= off) ? lds[t - off] : 0;
    __syncthreads();
    lds[t] += u;
    __syncthreads();
  }
  int excl = lds[t] - v + part[blockIdx.x];
  if (i < NN) { offs[i] = excl; deg[i] = excl; }  // deg becomes cursor
}

__global__ void k_scatter(const int* __restrict__ ei, int* __restrict__ cur,
                          int* __restrict__ csr) {
  int e = blockIdx.x * 256 + threadIdx.x;
  if (e >= ET) return;
  int s, d;
  if (e < E0) { s = ei[e]; d = ei[E0 + e]; } else { s = d = e - E0; }
  int pos = atomicAdd(&cur[d], 1);
  csr[pos] = s;
}

// ---------------- Layer-1 aggregation ----------------
// One wave per node. Lane holds 8 feats (16B bf16 load); half-waves process
// alternating edges (2/wave), 2x unroll -> 4 gathers in flight. Scores
// bounded -> plain sum of exp. Writes ELU(out+b1) in place over xr.
__global__ __launch_bounds__(256) void k_agg1(
    const unsigned short* __restrict__ xlb, float* __restrict__ xr_h,
    const int* __restrict__ offs, const int* __restrict__ csr,
    const float* __restrict__ att, const float* __restrict__ b1) {
  const int wave = threadIdx.x >> 6;
  const int lane = threadIdx.x & 63;
  const int n = blockIdx.x * 4 + wave;
  const int half = lane >> 5;
  const int sub = lane & 31;
  const int col = sub * 8;
  float xr8[8], at8[8];
  *(float4*)&xr8[0] = *(const float4*)&xr_h[(size_t)n * D1 + col];
  *(float4*)&xr8[4] = *(const float4*)&xr_h[(size_t)n * D1 + col + 4];
  *(float4*)&at8[0] = *(const float4*)&att[col];
  *(float4*)&at8[4] = *(const float4*)&att[col + 4];
  float l = 0.f;
  float acc[8] = {0.f, 0.f, 0.f, 0.f, 0.f, 0.f, 0.f, 0.f};
  const int beg = offs[n], fin = offs[n + 1];

  auto body = [&](uint4 w) {
    float xf[8];
    xf[0] = __uint_as_float(w.x << 16);  xf[1] = __uint_as_float(w.x & 0xffff0000u);
    xf[2] = __uint_as_float(w.y << 16);  xf[3] = __uint_as_float(w.y & 0xffff0000u);
    xf[4] = __uint_as_float(w.z << 16);  xf[5] = __uint_as_float(w.z & 0xffff0000u);
    xf[6] = __uint_as_float(w.w << 16);  xf[7] = __uint_as_float(w.w & 0xffff0000u);
    float c = 0.f;
#pragma unroll
    for (int k = 0; k < 8; ++k) {
      float v = xf[k] + xr8[k];
      v = fmaxf(v, 0.2f * v);
      c = fmaf(v, at8[k], c);
    }
    c += __shfl_xor(c, 1);
    c += __shfl_xor(c, 2);   // sum over the head's 4 lanes (32 feats)
    const float p = __expf(c);
    l += p;
#pragma unroll
    for (int k = 0; k < 8; ++k) acc[k] = fmaf(p, xf[k], acc[k]);
  };

  int idx = beg + half;
  for (; idx + 2 < fin; idx += 4) {
    const int s0 = csr[idx], s1 = csr[idx + 2];
    const uint4 w0 = *(const uint4*)&xlb[(size_t)s0 * D1 + col];
    const uint4 w1 = *(const uint4*)&xlb[(size_t)s1 * D1 + col];
    body(w0);
    body(w1);
  }
  for (; idx < fin; idx += 2) {
    const int s0 = csr[idx];
    const uint4 w0 = *(const uint4*)&xlb[(size_t)s0 * D1 + col];
    body(w0);
  }
  // merge halves (lane i and i+32 hold the same feats/head)
  l += __shfl_xor(l, 32);
#pragma unroll
  for (int k = 0; k < 8; ++k) acc[k] += __shfl_xor(acc[k], 32);
  if (half == 0) {
    const float rl = 1.f / (l + 1e-16f);
    float b8[8], o[8];
    *(float4*)&b8[0] = *(const float4*)&b1[col];
    *(float4*)&b8[4] = *(const float4*)&b1[col + 4];
#pragma unroll
    for (int k = 0; k < 8; ++k) {
      o[k] = acc[k] * rl + b8[k];
      o[k] = o[k] > 0.f ? o[k] : expm1f(o[k]);
    }
    *(float4*)&xr_h[(size_t)n * D1 + col] = *(float4*)&o[0];
    *(float4*)&xr_h[(size_t)n * D1 + col + 4] = *(float4*)&o[4];
  }
}

// ---------------- Layer-2 GEMM ----------------
// No LDS. Thread (i = t>>5, c = t&31) handles nodes n0+i+{0,8,16,24}.
// h float4 reads: 32 lanes sharing i read the same 16B line (L1/L2-resident).
// W2 (32 KB) stays L1-cached via scalar loads, amortized over 4 nodes.
__global__ __launch_bounds__(256) void k_gemm2(
    const float* __restrict__ h, const float* __restrict__ W2l,
    const float* __restrict__ W2r, float* __restrict__ h2l,
    float* __restrict__ h2r) {
  const int t = threadIdx.x;
  const int i = t >> 5, c = t & 31;
  const int n0 = blockIdx.x * 32 + i;     // n0 <= 49991, n0+8 <= 49999
  const float* W = (c < 16) ? W2l : W2r;
  float* outp = (c < 16) ? h2l : h2r;
  const int cc = c & 15;
  const bool g2 = n0 + 16 < NN, g3 = n0 + 24 < NN;
  const float* h0p = &h[(size_t)n0 * D1];
  const float* h1p = h0p + 8 * D1;
  const float* h2p = g2 ? h0p + 16 * D1 : h0p;
  const float* h3p = g3 ? h0p + 24 * D1 : h0p;
  float a0 = 0.f, a1 = 0.f, a2 = 0.f, a3 = 0.f;
#pragma unroll 4
  for (int k = 0; k < D1; k += 4) {
    const float w0 = W[k * 16 + cc];
    const float w1 = W[(k + 1) * 16 + cc];
    const float w2 = W[(k + 2) * 16 + cc];
    const float w3 = W[(k + 3) * 16 + cc];
    const float4 v0 = *(const float4*)&h0p[k];
    const float4 v1 = *(const float4*)&h1p[k];
    const float4 v2 = *(const float4*)&h2p[k];
    const float4 v3 = *(const float4*)&h3p[k];
    a0 = fmaf(v0.x, w0, fmaf(v0.y, w1, fmaf(v0.z, w2, fmaf(v0.w, w3, a0))));
    a1 = fmaf(v1.x, w0, fmaf(v1.y, w1, fmaf(v1.z, w2, fmaf(v1.w, w3, a1))));
    a2 = fmaf(v2.x, w0, fmaf(v2.y, w1, fmaf(v2.z, w2, fmaf(v2.w, w3, a2))));
    a3 = fmaf(v3.x, w0, fmaf(v3.y, w1, fmaf(v3.z, w2, fmaf(v3.w, w3, a3))));
  }
  outp[(size_t)n0 * C2 + cc] = a0;
  outp[(size_t)(n0 + 8) * C2 + cc] = a1;
  if (g2) outp[(size_t)(n0 + 16) * C2 + cc] = a2;
  if (g3) outp[(size_t)(n0 + 24) * C2 + cc] = a3;
}

// ---------------- Layer-2 aggregation ----------------
__global__ __launch_bounds__(256) void k_agg2(
    const float* __restrict__ h2l, const float* __restrict__ h2r,
    const int* __restrict__ offs, const int* __restrict__ csr,
    const float* __restrict__ att2, const float* __restrict__ b2,
    float* __restrict__ out) {
  const int wave = threadIdx.x >> 6;
  const int lane = threadIdx.x & 63;
  const int n = blockIdx.x * 4 + wave;
  if (n >= NN) return;
  const int c = lane & 15, g = lane >> 4;
  const float xr_v = h2r[(size_t)n * C2 + c];
  const float att_v = att2[c];
  float l = 0.f, acc = 0.f;
  const int beg = offs[n], fin = offs[n + 1];
  for (int idx = beg + g; idx < fin; idx += 4) {
    int s = csr[idx];
    float xlv = h2l[(size_t)s * C2 + c];
    float v = xlv + xr_v;
    v = fmaxf(v, 0.2f * v);
    float sc0 = v * att_v;
    sc0 += __shfl_xor(sc0, 1);
    sc0 += __shfl_xor(sc0, 2);
    sc0 += __shfl_xor(sc0, 4);
    sc0 += __shfl_xor(sc0, 8);
    float p = __expf(sc0);
    l += p;
    acc += p * xlv;
  }
  l += __shfl_xor(l, 16);   l += __shfl_xor(l, 32);
  acc += __shfl_xor(acc, 16); acc += __shfl_xor(acc, 32);
  float o = acc / (l + 1e-16f) + b2[c];
  o = o > 0.f ? o : 0.01f * o;
  if (lane < 16) out[(size_t)n * C2 + c] = o;
}

extern "C" void kernel_launch(void* const* d_in, const int* in_sizes, int n_in,
                              void* d_out, int out_size, void* d_ws, size_t ws_size,
                              hipStream_t stream) {
  const float* x    = (const float*)d_in[0];
  const int*   ei   = (const int*)d_in[1];
  const float* W1l  = (const float*)d_in[2];
  const float* W1r  = (const float*)d_in[3];
  const float* att1 = (const float*)d_in[4];
  const float* b1   = (const float*)d_in[5];
  const float* W2l  = (const float*)d_in[6];
  const float* W2r  = (const float*)d_in[7];
  const float* att2 = (const float*)d_in[8];
  const float* b2   = (const float*)d_in[9];
  float* out = (float*)d_out;

  // Workspace layout (~94 MB):
  unsigned short* xlb = (unsigned short*)d_ws;    // NN*D1 bf16 (25.6 MB)
  float* xr = (float*)(xlb + (size_t)NN * D1);    // NN*D1 f32, becomes h
  int* deg  = (int*)(xr + (size_t)NN * D1);       // NN (becomes cursor)
  int* offs = deg + NN;                           // NN+1
  int* csr  = offs + NN + 1;                      // ET
  int* part = csr + ET;                           // NB
  unsigned short* xb = (unsigned short*)(part + NB);  // MPAD*F1 bf16
  unsigned short* wt = xb + (size_t)MPAD * F1;        // 512*128 bf16
  float* h2l = (float*)xlb;                       // alias: xlb dead after agg1
  float* h2r = h2l + (size_t)NN * C2;

  hipMemsetAsync(deg, 0, NN * sizeof(int), stream);
  k_cvt_x<<<(MPAD * F1 / 4 + 255) / 256, 256, 0, stream>>>(x, xb);
  k_cvt_w<<<512 * F1 / 256, 256, 0, stream>>>(W1l, W1r, wt);
  k_gemm1m<<<dim3(MPAD / 128, 4), 256, 0, stream>>>(xb, wt, xlb, xr);
  k_hist<<<(ET + 255) / 256, 256, 0, stream>>>(ei, deg);
  k_scan_part<<<NB, 256, 0, stream>>>(deg, part);
  k_scan_top<<<1, 256, 0, stream>>>(part, offs);
  k_scan_apply<<<NB, 256, 0, stream>>>(deg, part, offs);
  k_scatter<<<(ET + 255) / 256, 256, 0, stream>>>(ei, deg, csr);
  k_agg1<<<NN / 4, 256, 0, stream>>>(xlb, xr, offs, csr, att1, b1);
  k_gemm2<<<(NN + 31) / 32, 256, 0, stream>>>(xr, W2l, W2r, h2l, h2r);
  k_agg2<<<NN / 4, 256, 0, stream>>>(h2l, h2r, offs, csr, att2, b2, out);
}

// Round 6
// 284.022 us; speedup vs baseline: 2.3769x; 1.1949x over previous
//
#include <hip/hip_runtime.h>
#include <math.h>

#define NN 50000
#define E0 640000
#define ET 690000   // E0 + NN self loops
#define F1 128
#define D1 256      // 8 heads * 32
#define C2 16
#define NB 196      // ceil(NN/256)
#define MPAD 50048  // 391*128, padded node count for MFMA tiles
#define PADK 136    // 128 + 8 bf16 pad (breaks ds_read_b128 bank conflicts)
#define PADK2 264   // 256 + 8 pad for gemm2 B tile

typedef __attribute__((ext_vector_type(8))) short bf16x8;
typedef __attribute__((ext_vector_type(4))) float f32x4;

__device__ __forceinline__ unsigned short f2bf(float f) {
  union { float f; unsigned u; } c; c.f = f;
  unsigned u = c.u + 0x7FFF + ((c.u >> 16) & 1);  // RNE
  return (unsigned short)(u >> 16);
}

// ---------------- converts ----------------
__global__ __launch_bounds__(256) void k_cvt_x(const float* __restrict__ x,
                                               unsigned short* __restrict__ xb) {
  long long i = (long long)(blockIdx.x * 256 + threadIdx.x) * 4;
  if (i >= (long long)MPAD * F1) return;
  float4 v = (i < (long long)NN * F1) ? *(const float4*)&x[i]
                                      : make_float4(0.f, 0.f, 0.f, 0.f);
  ushort4 o;
  o.x = f2bf(v.x); o.y = f2bf(v.y); o.z = f2bf(v.z); o.w = f2bf(v.w);
  *(ushort4*)&xb[i] = o;
}

// Wt[n][k] bf16, n in [0,512): cols 0..255 from W1l, 256..511 from W1r.
__global__ __launch_bounds__(256) void k_cvt_w(const float* __restrict__ Wl,
                                               const float* __restrict__ Wr,
                                               unsigned short* __restrict__ wt) {
  int tid = blockIdx.x * 256 + threadIdx.x;   // = n*128 + k
  int n = tid >> 7, k = tid & 127;
  float v = (n < 256) ? Wl[k * 256 + n] : Wr[k * 256 + (n - 256)];
  wt[tid] = f2bf(v);
}

// Wt2[n][k] bf16, n in [0,32): 0..15 from W2l, 16..31 from W2r. k in [0,256).
__global__ __launch_bounds__(256) void k_cvt_w2(const float* __restrict__ W2l,
                                                const float* __restrict__ W2r,
                                                unsigned short* __restrict__ wt2) {
  int tid = blockIdx.x * 256 + threadIdx.x;   // = n*256 + k
  int n = tid >> 8, k = tid & 255;
  float v = (n < 16) ? W2l[k * 16 + n] : W2r[k * 16 + (n - 16)];
  wt2[tid] = f2bf(v);
}

// ---------------- Layer-1 GEMM via MFMA ----------------
// C[M=50048, N=512] = xb @ Wt^T. xl half stored as bf16, xr half fp32.
__global__ __launch_bounds__(256) void k_gemm1m(
    const unsigned short* __restrict__ xb, const unsigned short* __restrict__ wt,
    unsigned short* __restrict__ xlb, float* __restrict__ xr) {
  __shared__ unsigned short Al[128 * PADK];
  __shared__ unsigned short Bl[128 * PADK];
  const int t = threadIdx.x;
  const int m0 = blockIdx.x * 128;
  const int n0 = blockIdx.y * 128;
  {
    const int r = t >> 4;             // 0..15
    const int c = (t & 15) * 8;       // bf16 offset within row
#pragma unroll
    for (int p = 0; p < 8; ++p) {
      const int row = r + p * 16;
      *(float4*)&Al[row * PADK + c] = *(const float4*)&xb[(size_t)(m0 + row) * F1 + c];
      *(float4*)&Bl[row * PADK + c] = *(const float4*)&wt[(size_t)(n0 + row) * F1 + c];
    }
  }
  __syncthreads();
  const int wave = t >> 6, lane = t & 63;
  const int mw = (wave >> 1) * 64, nw = (wave & 1) * 64;
  const int fr = lane & 15, fq = lane >> 4;
  f32x4 acc[4][4] = {};
#pragma unroll
  for (int ks = 0; ks < 4; ++ks) {
    const int ko = ks * 32 + fq * 8;
    bf16x8 a[4], b[4];
#pragma unroll
    for (int i = 0; i < 4; ++i)
      a[i] = *(const bf16x8*)&Al[(mw + i * 16 + fr) * PADK + ko];
#pragma unroll
    for (int j = 0; j < 4; ++j)
      b[j] = *(const bf16x8*)&Bl[(nw + j * 16 + fr) * PADK + ko];
#pragma unroll
    for (int i = 0; i < 4; ++i)
#pragma unroll
      for (int j = 0; j < 4; ++j)
        acc[i][j] = __builtin_amdgcn_mfma_f32_16x16x32_bf16(a[i], b[j], acc[i][j], 0, 0, 0);
  }
  if (n0 < 256) {  // xl half -> bf16
    const int cb = n0 + nw + fr;
#pragma unroll
    for (int i = 0; i < 4; ++i) {
      const int gm0 = m0 + mw + i * 16 + fq * 4;
#pragma unroll
      for (int j = 0; j < 4; ++j)
#pragma unroll
        for (int r = 0; r < 4; ++r) {
          const int gm = gm0 + r;
          if (gm < NN) xlb[(size_t)gm * D1 + cb + j * 16] = f2bf(acc[i][j][r]);
        }
    }
  } else {         // xr half -> fp32
    const int cb = (n0 - 256) + nw + fr;
#pragma unroll
    for (int i = 0; i < 4; ++i) {
      const int gm0 = m0 + mw + i * 16 + fq * 4;
#pragma unroll
      for (int j = 0; j < 4; ++j)
#pragma unroll
        for (int r = 0; r < 4; ++r) {
          const int gm = gm0 + r;
          if (gm < NN) xr[(size_t)gm * D1 + cb + j * 16] = acc[i][j][r];
        }
    }
  }
}

// ---------------- CSR build ----------------
__global__ void k_hist(const int* __restrict__ ei, int* __restrict__ deg) {
  int e = blockIdx.x * 256 + threadIdx.x;
  if (e >= ET) return;
  int d = (e < E0) ? ei[E0 + e] : (e - E0);
  atomicAdd(&deg[d], 1);
}

__global__ __launch_bounds__(256) void k_scan_part(const int* __restrict__ deg,
                                                   int* __restrict__ part) {
  int i = blockIdx.x * 256 + threadIdx.x;
  int v = (i < NN) ? deg[i] : 0;
  v += __shfl_xor(v, 1);  v += __shfl_xor(v, 2);  v += __shfl_xor(v, 4);
  v += __shfl_xor(v, 8);  v += __shfl_xor(v, 16); v += __shfl_xor(v, 32);
  __shared__ int w[4];
  if ((threadIdx.x & 63) == 0) w[threadIdx.x >> 6] = v;
  __syncthreads();
  if (threadIdx.x == 0) part[blockIdx.x] = w[0] + w[1] + w[2] + w[3];
}

__global__ __launch_bounds__(256) void k_scan_top(int* __restrict__ part,
                                                  int* __restrict__ offs) {
  __shared__ int lds[256];
  int t = threadIdx.x;
  int v = (t < NB) ? part[t] : 0;
  lds[t] = v;
  __syncthreads();
  for (int off = 1; off < 256; off <<= 1) {
    int u = (t >= off) ? lds[t - off] : 0;
    __syncthreads();
    lds[t] += u;
    __syncthreads();
  }
  if (t < NB) part[t] = lds[t] - v;
  if (t == 255) offs[NN] = lds[255];
}

__global__ __launch_bounds__(256) void k_scan_apply(int* __restrict__ deg,
                                                    const int* __restrict__ part,
                                                    int* __restrict__ offs) {
  __shared__ int lds[256];
  int t = threadIdx.x;
  int i = blockIdx.x * 256 + t;
  int v = (i < NN) ? deg[i] : 0;
  lds[t] = v;
  __syncthreads();
  for (int off = 1; off < 256; off <<= 1) {
    int u = (t >= off) ? lds[t - off] : 0;
    __syncthreads();
    lds[t] += u;
    __syncthreads();
  }
  int excl = lds[t] - v + part[blockIdx.x];
  if (i < NN) { offs[i] = excl; deg[i] = excl; }  // deg becomes cursor
}

__global__ void k_scatter(const int* __restrict__ ei, int* __restrict__ cur,
                          int* __restrict__ csr) {
  int e = blockIdx.x * 256 + threadIdx.x;
  if (e >= ET) return;
  int s, d;
  if (e < E0) { s = ei[e]; d = ei[E0 + e]; } else { s = d = e - E0; }
  int pos = atomicAdd(&cur[d], 1);
  csr[pos] = s;
}

// ---------------- Layer-1 aggregation ----------------
// One wave per node. Lane holds 8 feats (16B bf16 load); half-waves process
// alternating edges, 2x unroll -> 4 gathers in flight. Scores bounded ->
// plain sum of exp. Writes ELU(out+b1) as bf16 into hb (feeds MFMA gemm2).
__global__ __launch_bounds__(256) void k_agg1(
    const unsigned short* __restrict__ xlb, const float* __restrict__ xr,
    unsigned short* __restrict__ hb,
    const int* __restrict__ offs, const int* __restrict__ csr,
    const float* __restrict__ att, const float* __restrict__ b1) {
  const int wave = threadIdx.x >> 6;
  const int lane = threadIdx.x & 63;
  const int n = blockIdx.x * 4 + wave;
  const int half = lane >> 5;
  const int sub = lane & 31;
  const int col = sub * 8;
  float xr8[8], at8[8];
  *(float4*)&xr8[0] = *(const float4*)&xr[(size_t)n * D1 + col];
  *(float4*)&xr8[4] = *(const float4*)&xr[(size_t)n * D1 + col + 4];
  *(float4*)&at8[0] = *(const float4*)&att[col];
  *(float4*)&at8[4] = *(const float4*)&att[col + 4];
  float l = 0.f;
  float acc[8] = {0.f, 0.f, 0.f, 0.f, 0.f, 0.f, 0.f, 0.f};
  const int beg = offs[n], fin = offs[n + 1];

  auto body = [&](uint4 w) {
    float xf[8];
    xf[0] = __uint_as_float(w.x << 16);  xf[1] = __uint_as_float(w.x & 0xffff0000u);
    xf[2] = __uint_as_float(w.y << 16);  xf[3] = __uint_as_float(w.y & 0xffff0000u);
    xf[4] = __uint_as_float(w.z << 16);  xf[5] = __uint_as_float(w.z & 0xffff0000u);
    xf[6] = __uint_as_float(w.w << 16);  xf[7] = __uint_as_float(w.w & 0xffff0000u);
    float c = 0.f;
#pragma unroll
    for (int k = 0; k < 8; ++k) {
      float v = xf[k] + xr8[k];
      v = fmaxf(v, 0.2f * v);
      c = fmaf(v, at8[k], c);
    }
    c += __shfl_xor(c, 1);
    c += __shfl_xor(c, 2);   // sum over the head's 4 lanes (32 feats)
    const float p = __expf(c);
    l += p;
#pragma unroll
    for (int k = 0; k < 8; ++k) acc[k] = fmaf(p, xf[k], acc[k]);
  };

  int idx = beg + half;
  for (; idx + 2 < fin; idx += 4) {
    const int s0 = csr[idx], s1 = csr[idx + 2];
    const uint4 w0 = *(const uint4*)&xlb[(size_t)s0 * D1 + col];
    const uint4 w1 = *(const uint4*)&xlb[(size_t)s1 * D1 + col];
    body(w0);
    body(w1);
  }
  for (; idx < fin; idx += 2) {
    const int s0 = csr[idx];
    const uint4 w0 = *(const uint4*)&xlb[(size_t)s0 * D1 + col];
    body(w0);
  }
  // merge halves (lane i and i+32 hold the same feats/head)
  l += __shfl_xor(l, 32);
#pragma unroll
  for (int k = 0; k < 8; ++k) acc[k] += __shfl_xor(acc[k], 32);
  if (half == 0) {
    const float rl = 1.f / (l + 1e-16f);
    float b8[8], o[8];
    *(float4*)&b8[0] = *(const float4*)&b1[col];
    *(float4*)&b8[4] = *(const float4*)&b1[col + 4];
#pragma unroll
    for (int k = 0; k < 8; ++k) {
      o[k] = acc[k] * rl + b8[k];
      o[k] = o[k] > 0.f ? o[k] : expm1f(o[k]);
    }
    ushort4 p0, p1;
    p0.x = f2bf(o[0]); p0.y = f2bf(o[1]); p0.z = f2bf(o[2]); p0.w = f2bf(o[3]);
    p1.x = f2bf(o[4]); p1.y = f2bf(o[5]); p1.z = f2bf(o[6]); p1.w = f2bf(o[7]);
    *(ushort4*)&hb[(size_t)n * D1 + col] = p0;
    *(ushort4*)&hb[(size_t)n * D1 + col + 4] = p1;
  }
}

// ---------------- Layer-2 GEMM via MFMA ----------------
// h2[50000, 32] = hb @ Wt2^T. Block: 128 rows, 4 waves x 32 rows.
// Wave: 2x2 tiles of 16x16, K=256 in 8 steps. B staged in LDS (17 KB).
__global__ __launch_bounds__(256) void k_gemm2m(
    const unsigned short* __restrict__ hb, const unsigned short* __restrict__ wt2,
    float* __restrict__ h2l, float* __restrict__ h2r) {
  __shared__ unsigned short Bl[32 * PADK2];
  const int t = threadIdx.x;
  {
    const int n = t >> 3, k0 = (t & 7) * 32;
#pragma unroll
    for (int j = 0; j < 4; ++j)
      *(uint4*)&Bl[n * PADK2 + k0 + j * 8] = *(const uint4*)&wt2[n * 256 + k0 + j * 8];
  }
  __syncthreads();
  const int wave = t >> 6, lane = t & 63;
  const int fr = lane & 15, fq = lane >> 4;
  const int m0 = blockIdx.x * 128 + wave * 32;
  f32x4 acc[2][2] = {};
#pragma unroll
  for (int ks = 0; ks < 8; ++ks) {
    const int ko = ks * 32 + fq * 8;
    bf16x8 a[2], b[2];
#pragma unroll
    for (int i = 0; i < 2; ++i) {
      int row = m0 + i * 16 + fr; if (row >= NN) row = NN - 1;
      a[i] = *(const bf16x8*)&hb[(size_t)row * D1 + ko];
    }
#pragma unroll
    for (int j = 0; j < 2; ++j)
      b[j] = *(const bf16x8*)&Bl[(j * 16 + fr) * PADK2 + ko];
#pragma unroll
    for (int i = 0; i < 2; ++i)
#pragma unroll
      for (int j = 0; j < 2; ++j)
        acc[i][j] = __builtin_amdgcn_mfma_f32_16x16x32_bf16(a[i], b[j], acc[i][j], 0, 0, 0);
  }
#pragma unroll
  for (int i = 0; i < 2; ++i) {
    const int gm0 = m0 + i * 16 + fq * 4;
#pragma unroll
    for (int r = 0; r < 4; ++r) {
      const int gm = gm0 + r;
      if (gm < NN) {
        h2l[(size_t)gm * C2 + fr] = acc[i][0][r];
        h2r[(size_t)gm * C2 + fr] = acc[i][1][r];
      }
    }
  }
}

// ---------------- Layer-2 aggregation ----------------
__global__ __launch_bounds__(256) void k_agg2(
    const float* __restrict__ h2l, const float* __restrict__ h2r,
    const int* __restrict__ offs, const int* __restrict__ csr,
    const float* __restrict__ att2, const float* __restrict__ b2,
    float* __restrict__ out) {
  const int wave = threadIdx.x >> 6;
  const int lane = threadIdx.x & 63;
  const int n = blockIdx.x * 4 + wave;
  if (n >= NN) return;
  const int c = lane & 15, g = lane >> 4;
  const float xr_v = h2r[(size_t)n * C2 + c];
  const float att_v = att2[c];
  float l = 0.f, acc = 0.f;
  const int beg = offs[n], fin = offs[n + 1];
  for (int idx = beg + g; idx < fin; idx += 4) {
    int s = csr[idx];
    float xlv = h2l[(size_t)s * C2 + c];
    float v = xlv + xr_v;
    v = fmaxf(v, 0.2f * v);
    float sc0 = v * att_v;
    sc0 += __shfl_xor(sc0, 1);
    sc0 += __shfl_xor(sc0, 2);
    sc0 += __shfl_xor(sc0, 4);
    sc0 += __shfl_xor(sc0, 8);
    float p = __expf(sc0);
    l += p;
    acc += p * xlv;
  }
  l += __shfl_xor(l, 16);   l += __shfl_xor(l, 32);
  acc += __shfl_xor(acc, 16); acc += __shfl_xor(acc, 32);
  float o = acc / (l + 1e-16f) + b2[c];
  o = o > 0.f ? o : 0.01f * o;
  if (lane < 16) out[(size_t)n * C2 + c] = o;
}

extern "C" void kernel_launch(void* const* d_in, const int* in_sizes, int n_in,
                              void* d_out, int out_size, void* d_ws, size_t ws_size,
                              hipStream_t stream) {
  const float* x    = (const float*)d_in[0];
  const int*   ei   = (const int*)d_in[1];
  const float* W1l  = (const float*)d_in[2];
  const float* W1r  = (const float*)d_in[3];
  const float* att1 = (const float*)d_in[4];
  const float* b1   = (const float*)d_in[5];
  const float* W2l  = (const float*)d_in[6];
  const float* W2r  = (const float*)d_in[7];
  const float* att2 = (const float*)d_in[8];
  const float* b2   = (const float*)d_in[9];
  float* out = (float*)d_out;

  // Workspace layout (~119 MB):
  unsigned short* xlb = (unsigned short*)d_ws;    // NN*D1 bf16 (25.6 MB)
  float* xr = (float*)(xlb + (size_t)NN * D1);    // NN*D1 f32 (51.2 MB)
  unsigned short* hb = (unsigned short*)(xr + (size_t)NN * D1);  // NN*D1 bf16
  int* deg  = (int*)(hb + (size_t)NN * D1);       // NN (becomes cursor)
  int* offs = deg + NN;                           // NN+1
  int* csr  = offs + NN + 1;                      // ET
  int* part = csr + ET;                           // NB
  unsigned short* xb = (unsigned short*)(part + NB);  // MPAD*F1 bf16
  unsigned short* wt = xb + (size_t)MPAD * F1;        // 512*128 bf16
  unsigned short* wt2 = wt + 512 * F1;                // 32*256 bf16
  float* h2l = (float*)xlb;                       // alias: xlb dead after agg1
  float* h2r = h2l + (size_t)NN * C2;

  hipMemsetAsync(deg, 0, NN * sizeof(int), stream);
  k_cvt_x<<<(MPAD * F1 / 4 + 255) / 256, 256, 0, stream>>>(x, xb);
  k_cvt_w<<<512 * F1 / 256, 256, 0, stream>>>(W1l, W1r, wt);
  k_cvt_w2<<<32, 256, 0, stream>>>(W2l, W2r, wt2);
  k_gemm1m<<<dim3(MPAD / 128, 4), 256, 0, stream>>>(xb, wt, xlb, xr);
  k_hist<<<(ET + 255) / 256, 256, 0, stream>>>(ei, deg);
  k_scan_part<<<NB, 256, 0, stream>>>(deg, part);
  k_scan_top<<<1, 256, 0, stream>>>(part, offs);
  k_scan_apply<<<NB, 256, 0, stream>>>(deg, part, offs);
  k_scatter<<<(ET + 255) / 256, 256, 0, stream>>>(ei, deg, csr);
  k_agg1<<<NN / 4, 256, 0, stream>>>(xlb, xr, hb, offs, csr, att1, b1);
  k_gemm2m<<<(NN + 127) / 128, 256, 0, stream>>>(hb, wt2, h2l, h2r);
  k_agg2<<<NN / 4, 256, 0, stream>>>(h2l, h2r, offs, csr, att2, b2, out);
}

// Round 7
// 281.088 us; speedup vs baseline: 2.4017x; 1.0104x over previous
//
#include <hip/hip_runtime.h>
#include <math.h>

#define NN 50000
#define E0 640000
#define ET 690000   // E0 + NN self loops
#define F1 128
#define D1 256      // 8 heads * 32
#define C2 16
#define NB 196      // ceil(NN/256)
#define MPAD 50048  // 391*128, padded node count for MFMA tiles
#define PADK 136    // 128 + 8 pad (breaks ds_read_b128 bank conflicts)
#define PADK2 264   // 256 + 8 pad for gemm2 B tile

typedef _Float16 f16x8 __attribute__((ext_vector_type(8)));
typedef _Float16 h2 __attribute__((ext_vector_type(2)));
typedef __attribute__((ext_vector_type(4))) float f32x4;

__device__ __forceinline__ unsigned short f2h(float f) {
  union { _Float16 h; unsigned short u; } c;
  c.h = (_Float16)f;
  return c.u;
}
__device__ __forceinline__ h2 u2h2(unsigned u) {
  union { unsigned u; h2 h; } c; c.u = u; return c.h;
}
__device__ __forceinline__ unsigned h22u(h2 h) {
  union { h2 h; unsigned u; } c; c.h = h; return c.u;
}

// ---------------- converts ----------------
__global__ __launch_bounds__(256) void k_cvt_x(const float* __restrict__ x,
                                               unsigned short* __restrict__ xb) {
  long long i = (long long)(blockIdx.x * 256 + threadIdx.x) * 4;
  if (i >= (long long)MPAD * F1) return;
  float4 v = (i < (long long)NN * F1) ? *(const float4*)&x[i]
                                      : make_float4(0.f, 0.f, 0.f, 0.f);
  ushort4 o;
  o.x = f2h(v.x); o.y = f2h(v.y); o.z = f2h(v.z); o.w = f2h(v.w);
  *(ushort4*)&xb[i] = o;
}

// Fused weight converts: wt[n][k] (n<512, k<128) and wt2[n][k] (n<32, k<256).
__global__ __launch_bounds__(256) void k_cvt_w(
    const float* __restrict__ Wl, const float* __restrict__ Wr,
    const float* __restrict__ W2l, const float* __restrict__ W2r,
    unsigned short* __restrict__ wt, unsigned short* __restrict__ wt2) {
  const int b = blockIdx.x;
  if (b < 256) {
    int tid = b * 256 + threadIdx.x;   // = n*128 + k
    int n = tid >> 7, k = tid & 127;
    float v = (n < 256) ? Wl[k * 256 + n] : Wr[k * 256 + (n - 256)];
    wt[tid] = f2h(v);
  } else {
    int tid = (b - 256) * 256 + threadIdx.x;  // = n*256 + k
    int n = tid >> 8, k = tid & 255;
    float v = (n < 16) ? W2l[k * 16 + n] : W2r[k * 16 + (n - 16)];
    wt2[tid] = f2h(v);
  }
}

// ---------------- Layer-1 GEMM via MFMA (fp16) ----------------
// C[M=50048, N=512] = xb @ Wt^T. xl half stored fp16, xr half fp32.
__global__ __launch_bounds__(256) void k_gemm1m(
    const unsigned short* __restrict__ xb, const unsigned short* __restrict__ wt,
    unsigned short* __restrict__ xlh, float* __restrict__ xr) {
  __shared__ unsigned short Al[128 * PADK];
  __shared__ unsigned short Bl[128 * PADK];
  const int t = threadIdx.x;
  const int m0 = blockIdx.x * 128;
  const int n0 = blockIdx.y * 128;
  {
    const int r = t >> 4;             // 0..15
    const int c = (t & 15) * 8;
#pragma unroll
    for (int p = 0; p < 8; ++p) {
      const int row = r + p * 16;
      *(float4*)&Al[row * PADK + c] = *(const float4*)&xb[(size_t)(m0 + row) * F1 + c];
      *(float4*)&Bl[row * PADK + c] = *(const float4*)&wt[(size_t)(n0 + row) * F1 + c];
    }
  }
  __syncthreads();
  const int wave = t >> 6, lane = t & 63;
  const int mw = (wave >> 1) * 64, nw = (wave & 1) * 64;
  const int fr = lane & 15, fq = lane >> 4;
  f32x4 acc[4][4] = {};
#pragma unroll
  for (int ks = 0; ks < 4; ++ks) {
    const int ko = ks * 32 + fq * 8;
    f16x8 a[4], b[4];
#pragma unroll
    for (int i = 0; i < 4; ++i)
      a[i] = *(const f16x8*)&Al[(mw + i * 16 + fr) * PADK + ko];
#pragma unroll
    for (int j = 0; j < 4; ++j)
      b[j] = *(const f16x8*)&Bl[(nw + j * 16 + fr) * PADK + ko];
#pragma unroll
    for (int i = 0; i < 4; ++i)
#pragma unroll
      for (int j = 0; j < 4; ++j)
        acc[i][j] = __builtin_amdgcn_mfma_f32_16x16x32_f16(a[i], b[j], acc[i][j], 0, 0, 0);
  }
  if (n0 < 256) {  // xl half -> fp16
    const int cb = n0 + nw + fr;
#pragma unroll
    for (int i = 0; i < 4; ++i) {
      const int gm0 = m0 + mw + i * 16 + fq * 4;
#pragma unroll
      for (int j = 0; j < 4; ++j)
#pragma unroll
        for (int r = 0; r < 4; ++r) {
          const int gm = gm0 + r;
          if (gm < NN) xlh[(size_t)gm * D1 + cb + j * 16] = f2h(acc[i][j][r]);
        }
    }
  } else {         // xr half -> fp32
    const int cb = (n0 - 256) + nw + fr;
#pragma unroll
    for (int i = 0; i < 4; ++i) {
      const int gm0 = m0 + mw + i * 16 + fq * 4;
#pragma unroll
      for (int j = 0; j < 4; ++j)
#pragma unroll
        for (int r = 0; r < 4; ++r) {
          const int gm = gm0 + r;
          if (gm < NN) xr[(size_t)gm * D1 + cb + j * 16] = acc[i][j][r];
        }
    }
  }
}

// ---------------- CSR build ----------------
__global__ void k_hist(const int* __restrict__ ei, int* __restrict__ deg) {
  int e = blockIdx.x * 256 + threadIdx.x;
  if (e >= ET) return;
  int d = (e < E0) ? ei[E0 + e] : (e - E0);
  atomicAdd(&deg[d], 1);
}

__global__ __launch_bounds__(256) void k_scan_part(const int* __restrict__ deg,
                                                   int* __restrict__ part) {
  int i = blockIdx.x * 256 + threadIdx.x;
  int v = (i < NN) ? deg[i] : 0;
  v += __shfl_xor(v, 1);  v += __shfl_xor(v, 2);  v += __shfl_xor(v, 4);
  v += __shfl_xor(v, 8);  v += __shfl_xor(v, 16); v += __shfl_xor(v, 32);
  __shared__ int w[4];
  if ((threadIdx.x & 63) == 0) w[threadIdx.x >> 6] = v;
  __syncthreads();
  if (threadIdx.x == 0) part[blockIdx.x] = w[0] + w[1] + w[2] + w[3];
}

__global__ __launch_bounds__(256) void k_scan_top(int* __restrict__ part,
                                                  int* __restrict__ offs) {
  __shared__ int lds[256];
  int t = threadIdx.x;
  int v = (t < NB) ? part[t] : 0;
  lds[t] = v;
  __syncthreads();
  for (int off = 1; off < 256; off <<= 1) {
    int u = (t >= off) ? lds[t - off] : 0;
    __syncthreads();
    lds[t] += u;
    __syncthreads();
  }
  if (t < NB) part[t] = lds[t] - v;
  if (t == 255) offs[NN] = lds[255];
}

__global__ __launch_bounds__(256) void k_scan_apply(int* __restrict__ deg,
                                                    const int* __restrict__ part,
                                                    int* __restrict__ offs) {
  __shared__ int lds[256];
  int t = threadIdx.x;
  int i = blockIdx.x * 256 + t;
  int v = (i < NN) ? deg[i] : 0;
  lds[t] = v;
  __syncthreads();
  for (int off = 1; off < 256; off <<= 1) {
    int u = (t >= off) ? lds[t - off] : 0;
    __syncthreads();
    lds[t] += u;
    __syncthreads();
  }
  int excl = lds[t] - v + part[blockIdx.x];
  if (i < NN) { offs[i] = excl; deg[i] = excl; }  // deg becomes cursor
}

__global__ void k_scatter(const int* __restrict__ ei, int* __restrict__ cur,
                          int* __restrict__ csr) {
  int e = blockIdx.x * 256 + threadIdx.x;
  if (e >= ET) return;
  int s, d;
  if (e < E0) { s = ei[e]; d = ei[E0 + e]; } else { s = d = e - E0; }
  int pos = atomicAdd(&cur[d], 1);
  csr[pos] = s;
}

// ---------------- Layer-1 aggregation (packed fp16) ----------------
// One wave per node; half-waves alternate edges, 2x unroll (4 gathers in
// flight). Lane holds 8 feats = 4 fp16 pairs. leaky(v)=0.6v+0.4|v| =>
// score = 0.6*fdot2(v,att)+0.4*fdot2(|v|,att); accumulate via v_pk_fma_f16.
// Scores bounded -> plain sum of exp. Writes ELU(out+b1) fp16 into hb.
__global__ __launch_bounds__(256) void k_agg1(
    const unsigned short* __restrict__ xlh, const float* __restrict__ xr,
    unsigned short* __restrict__ hb,
    const int* __restrict__ offs, const int* __restrict__ csr,
    const float* __restrict__ att, const float* __restrict__ b1) {
  const int wave = threadIdx.x >> 6;
  const int lane = threadIdx.x & 63;
  const int n = blockIdx.x * 4 + wave;
  const int half = lane >> 5;
  const int sub = lane & 31;
  const int col = sub * 8;
  float xr8[8], at8[8];
  *(float4*)&xr8[0] = *(const float4*)&xr[(size_t)n * D1 + col];
  *(float4*)&xr8[4] = *(const float4*)&xr[(size_t)n * D1 + col + 4];
  *(float4*)&at8[0] = *(const float4*)&att[col];
  *(float4*)&at8[4] = *(const float4*)&att[col + 4];
  h2 xrh[4], ath[4];
#pragma unroll
  for (int j = 0; j < 4; ++j) {
    xrh[j] = h2{(_Float16)xr8[2 * j], (_Float16)xr8[2 * j + 1]};
    ath[j] = h2{(_Float16)at8[2 * j], (_Float16)at8[2 * j + 1]};
  }
  float l = 0.f;
  h2 acc2[4] = {h2{0, 0}, h2{0, 0}, h2{0, 0}, h2{0, 0}};
  const int beg = offs[n], fin = offs[n + 1];

  auto body = [&](uint4 w) {
    h2 xh[4];
    xh[0] = u2h2(w.x); xh[1] = u2h2(w.y); xh[2] = u2h2(w.z); xh[3] = u2h2(w.w);
    float c1 = 0.f, c2 = 0.f;
#pragma unroll
    for (int j = 0; j < 4; ++j) {
      h2 v = xh[j] + xrh[j];
      h2 a = u2h2(h22u(v) & 0x7FFF7FFFu);       // |v| per half
      c1 = __builtin_amdgcn_fdot2(v, ath[j], c1, false);
      c2 = __builtin_amdgcn_fdot2(a, ath[j], c2, false);
    }
    float c = 0.6f * c1 + 0.4f * c2;
    c += __shfl_xor(c, 1);
    c += __shfl_xor(c, 2);   // sum over the head's 4 lanes (32 feats)
    const float p = __expf(c);
    l += p;
    const _Float16 ph = (_Float16)p;
    const h2 p2 = h2{ph, ph};
#pragma unroll
    for (int j = 0; j < 4; ++j) acc2[j] += p2 * xh[j];   // v_pk_fma_f16
  };

  int idx = beg + half;
  for (; idx + 2 < fin; idx += 4) {
    const int s0 = csr[idx], s1 = csr[idx + 2];
    const uint4 w0 = *(const uint4*)&xlh[(size_t)s0 * D1 + col];
    const uint4 w1 = *(const uint4*)&xlh[(size_t)s1 * D1 + col];
    body(w0);
    body(w1);
  }
  for (; idx < fin; idx += 2) {
    const int s0 = csr[idx];
    const uint4 w0 = *(const uint4*)&xlh[(size_t)s0 * D1 + col];
    body(w0);
  }
  // merge halves (lane i and i+32 hold the same feats/head)
  l += __shfl_xor(l, 32);
#pragma unroll
  for (int j = 0; j < 4; ++j) {
    unsigned u = h22u(acc2[j]);
    u = __shfl_xor((int)u, 32);
    acc2[j] += u2h2(u);
  }
  if (half == 0) {
    const float rl = 1.f / (l + 1e-16f);
    float b8[8], o[8];
    *(float4*)&b8[0] = *(const float4*)&b1[col];
    *(float4*)&b8[4] = *(const float4*)&b1[col + 4];
#pragma unroll
    for (int j = 0; j < 4; ++j) {
      o[2 * j]     = (float)acc2[j][0] * rl + b8[2 * j];
      o[2 * j + 1] = (float)acc2[j][1] * rl + b8[2 * j + 1];
    }
#pragma unroll
    for (int k = 0; k < 8; ++k) o[k] = o[k] > 0.f ? o[k] : expm1f(o[k]);
    ushort4 p0, p1;
    p0.x = f2h(o[0]); p0.y = f2h(o[1]); p0.z = f2h(o[2]); p0.w = f2h(o[3]);
    p1.x = f2h(o[4]); p1.y = f2h(o[5]); p1.z = f2h(o[6]); p1.w = f2h(o[7]);
    *(ushort4*)&hb[(size_t)n * D1 + col] = p0;
    *(ushort4*)&hb[(size_t)n * D1 + col + 4] = p1;
  }
}

// ---------------- Layer-2 GEMM via MFMA (fp16) ----------------
// h2[50000, 32] = hb @ Wt2^T. Block: 128 rows, 4 waves x 32 rows.
__global__ __launch_bounds__(256) void k_gemm2m(
    const unsigned short* __restrict__ hb, const unsigned short* __restrict__ wt2,
    float* __restrict__ h2l, float* __restrict__ h2r) {
  __shared__ unsigned short Bl[32 * PADK2];
  const int t = threadIdx.x;
  {
    const int n = t >> 3, k0 = (t & 7) * 32;
#pragma unroll
    for (int j = 0; j < 4; ++j)
      *(uint4*)&Bl[n * PADK2 + k0 + j * 8] = *(const uint4*)&wt2[n * 256 + k0 + j * 8];
  }
  __syncthreads();
  const int wave = t >> 6, lane = t & 63;
  const int fr = lane & 15, fq = lane >> 4;
  const int m0 = blockIdx.x * 128 + wave * 32;
  f32x4 acc[2][2] = {};
#pragma unroll
  for (int ks = 0; ks < 8; ++ks) {
    const int ko = ks * 32 + fq * 8;
    f16x8 a[2], b[2];
#pragma unroll
    for (int i = 0; i < 2; ++i) {
      int row = m0 + i * 16 + fr; if (row >= NN) row = NN - 1;
      a[i] = *(const f16x8*)&hb[(size_t)row * D1 + ko];
    }
#pragma unroll
    for (int j = 0; j < 2; ++j)
      b[j] = *(const f16x8*)&Bl[(j * 16 + fr) * PADK2 + ko];
#pragma unroll
    for (int i = 0; i < 2; ++i)
#pragma unroll
      for (int j = 0; j < 2; ++j)
        acc[i][j] = __builtin_amdgcn_mfma_f32_16x16x32_f16(a[i], b[j], acc[i][j], 0, 0, 0);
  }
#pragma unroll
  for (int i = 0; i < 2; ++i) {
    const int gm0 = m0 + i * 16 + fq * 4;
#pragma unroll
    for (int r = 0; r < 4; ++r) {
      const int gm = gm0 + r;
      if (gm < NN) {
        h2l[(size_t)gm * C2 + fr] = acc[i][0][r];
        h2r[(size_t)gm * C2 + fr] = acc[i][1][r];
      }
    }
  }
}

// ---------------- Layer-2 aggregation ----------------
__global__ __launch_bounds__(256) void k_agg2(
    const float* __restrict__ h2l, const float* __restrict__ h2r,
    const int* __restrict__ offs, const int* __restrict__ csr,
    const float* __restrict__ att2, const float* __restrict__ b2,
    float* __restrict__ out) {
  const int wave = threadIdx.x >> 6;
  const int lane = threadIdx.x & 63;
  const int n = blockIdx.x * 4 + wave;
  if (n >= NN) return;
  const int c = lane & 15, g = lane >> 4;
  const float xr_v = h2r[(size_t)n * C2 + c];
  const float att_v = att2[c];
  float l = 0.f, acc = 0.f;
  const int beg = offs[n], fin = offs[n + 1];
  for (int idx = beg + g; idx < fin; idx += 4) {
    int s = csr[idx];
    float xlv = h2l[(size_t)s * C2 + c];
    float v = xlv + xr_v;
    v = fmaxf(v, 0.2f * v);
    float sc0 = v * att_v;
    sc0 += __shfl_xor(sc0, 1);
    sc0 += __shfl_xor(sc0, 2);
    sc0 += __shfl_xor(sc0, 4);
    sc0 += __shfl_xor(sc0, 8);
    float p = __expf(sc0);
    l += p;
    acc += p * xlv;
  }
  l += __shfl_xor(l, 16);   l += __shfl_xor(l, 32);
  acc += __shfl_xor(acc, 16); acc += __shfl_xor(acc, 32);
  float o = acc / (l + 1e-16f) + b2[c];
  o = o > 0.f ? o : 0.01f * o;
  if (lane < 16) out[(size_t)n * C2 + c] = o;
}

extern "C" void kernel_launch(void* const* d_in, const int* in_sizes, int n_in,
                              void* d_out, int out_size, void* d_ws, size_t ws_size,
                              hipStream_t stream) {
  const float* x    = (const float*)d_in[0];
  const int*   ei   = (const int*)d_in[1];
  const float* W1l  = (const float*)d_in[2];
  const float* W1r  = (const float*)d_in[3];
  const float* att1 = (const float*)d_in[4];
  const float* b1   = (const float*)d_in[5];
  const float* W2l  = (const float*)d_in[6];
  const float* W2r  = (const float*)d_in[7];
  const float* att2 = (const float*)d_in[8];
  const float* b2   = (const float*)d_in[9];
  float* out = (float*)d_out;

  // Workspace layout (~119 MB):
  unsigned short* xlh = (unsigned short*)d_ws;    // NN*D1 fp16 (25.6 MB)
  float* xr = (float*)(xlh + (size_t)NN * D1);    // NN*D1 f32 (51.2 MB)
  unsigned short* hb = (unsigned short*)(xr + (size_t)NN * D1);  // NN*D1 fp16
  int* deg  = (int*)(hb + (size_t)NN * D1);       // NN (becomes cursor)
  int* offs = deg + NN;                           // NN+1
  int* csr  = offs + NN + 1;                      // ET
  int* part = csr + ET;                           // NB
  unsigned short* xb = (unsigned short*)(part + NB);  // MPAD*F1 fp16
  unsigned short* wt = xb + (size_t)MPAD * F1;        // 512*128 fp16
  unsigned short* wt2 = wt + 512 * F1;                // 32*256 fp16
  float* h2l = (float*)xlh;                       // alias: xlh dead after agg1
  float* h2r = h2l + (size_t)NN * C2;

  hipMemsetAsync(deg, 0, NN * sizeof(int), stream);
  k_cvt_x<<<(MPAD * F1 / 4 + 255) / 256, 256, 0, stream>>>(x, xb);
  k_cvt_w<<<288, 256, 0, stream>>>(W1l, W1r, W2l, W2r, wt, wt2);
  k_gemm1m<<<dim3(MPAD / 128, 4), 256, 0, stream>>>(xb, wt, xlh, xr);
  k_hist<<<(ET + 255) / 256, 256, 0, stream>>>(ei, deg);
  k_scan_part<<<NB, 256, 0, stream>>>(deg, part);
  k_scan_top<<<1, 256, 0, stream>>>(part, offs);
  k_scan_apply<<<NB, 256, 0, stream>>>(deg, part, offs);
  k_scatter<<<(ET + 255) / 256, 256, 0, stream>>>(ei, deg, csr);
  k_agg1<<<NN / 4, 256, 0, stream>>>(xlh, xr, hb, offs, csr, att1, b1);
  k_gemm2m<<<(NN + 127) / 128, 256, 0, stream>>>(hb, wt2, h2l, h2r);
  k_agg2<<<NN / 4, 256, 0, stream>>>(h2l, h2r, offs, csr, att2, b2, out);
}

// Round 8
// 270.499 us; speedup vs baseline: 2.4957x; 1.0391x over previous
//
#include <hip/hip_runtime.h>
#include <math.h>

#define NN 50000
#define E0 640000
#define ET 690000   // E0 + NN self loops
#define F1 128
#define D1 256      // 8 heads * 32
#define C2 16
#define NB 196      // ceil(NN/256)
#define MPAD 50048  // 391*128, padded node count for MFMA tiles
#define PADK 136    // 128 + 8 pad (breaks ds_read_b128 bank conflicts)
#define PADK2 264   // 256 + 8 pad for gemm2 B tile
#define LOG2E 1.4426950408889634f

typedef _Float16 f16x8 __attribute__((ext_vector_type(8)));
typedef _Float16 h2 __attribute__((ext_vector_type(2)));
typedef __attribute__((ext_vector_type(4))) float f32x4;

__device__ __forceinline__ unsigned short f2h(float f) {
  union { _Float16 h; unsigned short u; } c;
  c.h = (_Float16)f;
  return c.u;
}
__device__ __forceinline__ float h2f(unsigned short u) {
  union { unsigned short u; _Float16 h; } c; c.u = u; return (float)c.h;
}
__device__ __forceinline__ h2 u2h2(unsigned u) {
  union { unsigned u; h2 h; } c; c.u = u; return c.h;
}
__device__ __forceinline__ unsigned h22u(h2 h) {
  union { h2 h; unsigned u; } c; c.h = h; return c.u;
}

// ---------------- fused prep: cvt_x | cvt_w | hist ----------------
// blocks [0,6256): x->fp16 (+pad)   [6256,6544): weights->fp16   rest: degree hist
__global__ __launch_bounds__(256) void k_prep(
    const float* __restrict__ x, const float* __restrict__ Wl,
    const float* __restrict__ Wr, const float* __restrict__ W2l,
    const float* __restrict__ W2r, const int* __restrict__ ei,
    unsigned short* __restrict__ xb, unsigned short* __restrict__ wt,
    unsigned short* __restrict__ wt2, int* __restrict__ deg) {
  const int b = blockIdx.x;
  if (b < 6256) {
    long long i = (long long)(b * 256 + threadIdx.x) * 4;
    if (i >= (long long)MPAD * F1) return;
    float4 v = (i < (long long)NN * F1) ? *(const float4*)&x[i]
                                        : make_float4(0.f, 0.f, 0.f, 0.f);
    ushort4 o;
    o.x = f2h(v.x); o.y = f2h(v.y); o.z = f2h(v.z); o.w = f2h(v.w);
    *(ushort4*)&xb[i] = o;
  } else if (b < 6512) {
    int tid = (b - 6256) * 256 + threadIdx.x;   // = n*128 + k
    int n = tid >> 7, k = tid & 127;
    float v = (n < 256) ? Wl[k * 256 + n] : Wr[k * 256 + (n - 256)];
    wt[tid] = f2h(v);
  } else if (b < 6544) {
    int tid = (b - 6512) * 256 + threadIdx.x;   // = n*256 + k
    int n = tid >> 8, k = tid & 255;
    float v = (n < 16) ? W2l[k * 16 + n] : W2r[k * 16 + (n - 16)];
    wt2[tid] = f2h(v);
  } else {
    int e = (b - 6544) * 256 + threadIdx.x;
    if (e >= ET) return;
    int d = (e < E0) ? ei[E0 + e] : (e - E0);
    atomicAdd(&deg[d], 1);
  }
}

// ---------------- Layer-1 GEMM via MFMA (fp16) ----------------
// C[M=50048, N=512] = xb @ Wt^T. Both halves stored fp16.
__global__ __launch_bounds__(256) void k_gemm1m(
    const unsigned short* __restrict__ xb, const unsigned short* __restrict__ wt,
    unsigned short* __restrict__ xlh, unsigned short* __restrict__ xrh) {
  __shared__ unsigned short Al[128 * PADK];
  __shared__ unsigned short Bl[128 * PADK];
  const int t = threadIdx.x;
  const int m0 = blockIdx.x * 128;
  const int n0 = blockIdx.y * 128;
  {
    const int r = t >> 4;             // 0..15
    const int c = (t & 15) * 8;
#pragma unroll
    for (int p = 0; p < 8; ++p) {
      const int row = r + p * 16;
      *(float4*)&Al[row * PADK + c] = *(const float4*)&xb[(size_t)(m0 + row) * F1 + c];
      *(float4*)&Bl[row * PADK + c] = *(const float4*)&wt[(size_t)(n0 + row) * F1 + c];
    }
  }
  __syncthreads();
  const int wave = t >> 6, lane = t & 63;
  const int mw = (wave >> 1) * 64, nw = (wave & 1) * 64;
  const int fr = lane & 15, fq = lane >> 4;
  f32x4 acc[4][4] = {};
#pragma unroll
  for (int ks = 0; ks < 4; ++ks) {
    const int ko = ks * 32 + fq * 8;
    f16x8 a[4], b[4];
#pragma unroll
    for (int i = 0; i < 4; ++i)
      a[i] = *(const f16x8*)&Al[(mw + i * 16 + fr) * PADK + ko];
#pragma unroll
    for (int j = 0; j < 4; ++j)
      b[j] = *(const f16x8*)&Bl[(nw + j * 16 + fr) * PADK + ko];
#pragma unroll
    for (int i = 0; i < 4; ++i)
#pragma unroll
      for (int j = 0; j < 4; ++j)
        acc[i][j] = __builtin_amdgcn_mfma_f32_16x16x32_f16(a[i], b[j], acc[i][j], 0, 0, 0);
  }
  unsigned short* outp = (n0 < 256) ? xlh : xrh;
  const int cb = (n0 & 255) + nw + fr;
#pragma unroll
  for (int i = 0; i < 4; ++i) {
    const int gm0 = m0 + mw + i * 16 + fq * 4;
#pragma unroll
    for (int j = 0; j < 4; ++j)
#pragma unroll
      for (int r = 0; r < 4; ++r) {
        const int gm = gm0 + r;
        if (gm < NN) outp[(size_t)gm * D1 + cb + j * 16] = f2h(acc[i][j][r]);
      }
  }
}

// ---------------- CSR scan/scatter ----------------
__global__ __launch_bounds__(256) void k_scan_part(const int* __restrict__ deg,
                                                   int* __restrict__ part) {
  int i = blockIdx.x * 256 + threadIdx.x;
  int v = (i < NN) ? deg[i] : 0;
  v += __shfl_xor(v, 1);  v += __shfl_xor(v, 2);  v += __shfl_xor(v, 4);
  v += __shfl_xor(v, 8);  v += __shfl_xor(v, 16); v += __shfl_xor(v, 32);
  __shared__ int w[4];
  if ((threadIdx.x & 63) == 0) w[threadIdx.x >> 6] = v;
  __syncthreads();
  if (threadIdx.x == 0) part[blockIdx.x] = w[0] + w[1] + w[2] + w[3];
}

__global__ __launch_bounds__(256) void k_scan_top(int* __restrict__ part,
                                                  int* __restrict__ offs) {
  __shared__ int lds[256];
  int t = threadIdx.x;
  int v = (t < NB) ? part[t] : 0;
  lds[t] = v;
  __syncthreads();
  for (int off = 1; off < 256; off <<= 1) {
    int u = (t >= off) ? lds[t - off] : 0;
    __syncthreads();
    lds[t] += u;
    __syncthreads();
  }
  if (t < NB) part[t] = lds[t] - v;
  if (t == 255) offs[NN] = lds[255];
}

__global__ __launch_bounds__(256) void k_scan_apply(int* __restrict__ deg,
                                                    const int* __restrict__ part,
                                                    int* __restrict__ offs) {
  __shared__ int lds[256];
  int t = threadIdx.x;
  int i = blockIdx.x * 256 + t;
  int v = (i < NN) ? deg[i] : 0;
  lds[t] = v;
  __syncthreads();
  for (int off = 1; off < 256; off <<= 1) {
    int u = (t >= off) ? lds[t - off] : 0;
    __syncthreads();
    lds[t] += u;
    __syncthreads();
  }
  int excl = lds[t] - v + part[blockIdx.x];
  if (i < NN) { offs[i] = excl; deg[i] = excl; }  // deg becomes cursor
}

__global__ void k_scatter(const int* __restrict__ ei, int* __restrict__ cur,
                          int* __restrict__ csr) {
  int e = blockIdx.x * 256 + threadIdx.x;
  if (e >= ET) return;
  int s, d;
  if (e < E0) { s = ei[e]; d = ei[E0 + e]; } else { s = d = e - E0; }
  int pos = atomicAdd(&cur[d], 1);
  csr[pos] = s;
}

// ---------------- Layer-1 aggregation (packed fp16) ----------------
// One wave per node; half-waves alternate edges, 3x unroll (6 gathers in
// flight). leaky folded: score exponent c = fdot2(v,0.6*log2e*att) +
// fdot2(|v|,0.4*log2e*att); p = exp2(c). Writes ELU(out+b1) fp16 into hb.
__global__ __launch_bounds__(256) void k_agg1(
    const unsigned short* __restrict__ xlh, const unsigned short* __restrict__ xrh,
    unsigned short* __restrict__ hb,
    const int* __restrict__ offs, const int* __restrict__ csr,
    const float* __restrict__ att, const float* __restrict__ b1) {
  const int wave = threadIdx.x >> 6;
  const int lane = threadIdx.x & 63;
  const int n = blockIdx.x * 4 + wave;
  const int half = lane >> 5;
  const int sub = lane & 31;
  const int col = sub * 8;
  const uint4 xru = *(const uint4*)&xrh[(size_t)n * D1 + col];
  h2 xr2[4];
  xr2[0] = u2h2(xru.x); xr2[1] = u2h2(xru.y);
  xr2[2] = u2h2(xru.z); xr2[3] = u2h2(xru.w);
  float at8[8];
  *(float4*)&at8[0] = *(const float4*)&att[col];
  *(float4*)&at8[4] = *(const float4*)&att[col + 4];
  h2 ath6[4], ath4[4];
#pragma unroll
  for (int j = 0; j < 4; ++j) {
    ath6[j] = h2{(_Float16)(at8[2 * j] * (0.6f * LOG2E)),
                 (_Float16)(at8[2 * j + 1] * (0.6f * LOG2E))};
    ath4[j] = h2{(_Float16)(at8[2 * j] * (0.4f * LOG2E)),
                 (_Float16)(at8[2 * j + 1] * (0.4f * LOG2E))};
  }
  float l = 0.f;
  h2 acc2[4] = {h2{0, 0}, h2{0, 0}, h2{0, 0}, h2{0, 0}};
  const int beg = offs[n], fin = offs[n + 1];

  auto body = [&](uint4 w) {
    h2 xh[4];
    xh[0] = u2h2(w.x); xh[1] = u2h2(w.y); xh[2] = u2h2(w.z); xh[3] = u2h2(w.w);
    float c = 0.f;
#pragma unroll
    for (int j = 0; j < 4; ++j) {
      h2 v = xh[j] + xr2[j];
      h2 a = u2h2(h22u(v) & 0x7FFF7FFFu);       // |v| per half
      c = __builtin_amdgcn_fdot2(v, ath6[j], c, false);
      c = __builtin_amdgcn_fdot2(a, ath4[j], c, false);
    }
    c += __shfl_xor(c, 1);
    c += __shfl_xor(c, 2);   // sum over the head's 4 lanes (32 feats)
    const float p = exp2f(c);
    l += p;
    const _Float16 ph = (_Float16)p;
    const h2 p2 = h2{ph, ph};
#pragma unroll
    for (int j = 0; j < 4; ++j) acc2[j] += p2 * xh[j];   // v_pk_fma_f16
  };

  int idx = beg + half;
  for (; idx + 4 < fin; idx += 6) {
    const int s0 = csr[idx], s1 = csr[idx + 2], s2 = csr[idx + 4];
    const uint4 w0 = *(const uint4*)&xlh[(size_t)s0 * D1 + col];
    const uint4 w1 = *(const uint4*)&xlh[(size_t)s1 * D1 + col];
    const uint4 w2 = *(const uint4*)&xlh[(size_t)s2 * D1 + col];
    body(w0);
    body(w1);
    body(w2);
  }
  for (; idx < fin; idx += 2) {
    const int s0 = csr[idx];
    const uint4 w0 = *(const uint4*)&xlh[(size_t)s0 * D1 + col];
    body(w0);
  }
  // merge halves (lane i and i+32 hold the same feats/head)
  l += __shfl_xor(l, 32);
#pragma unroll
  for (int j = 0; j < 4; ++j) {
    unsigned u = h22u(acc2[j]);
    u = __shfl_xor((int)u, 32);
    acc2[j] += u2h2(u);
  }
  if (half == 0) {
    const float rl = 1.f / (l + 1e-16f);
    float b8[8], o[8];
    *(float4*)&b8[0] = *(const float4*)&b1[col];
    *(float4*)&b8[4] = *(const float4*)&b1[col + 4];
#pragma unroll
    for (int j = 0; j < 4; ++j) {
      o[2 * j]     = (float)acc2[j][0] * rl + b8[2 * j];
      o[2 * j + 1] = (float)acc2[j][1] * rl + b8[2 * j + 1];
    }
#pragma unroll
    for (int k = 0; k < 8; ++k) o[k] = o[k] > 0.f ? o[k] : expm1f(o[k]);
    ushort4 p0, p1;
    p0.x = f2h(o[0]); p0.y = f2h(o[1]); p0.z = f2h(o[2]); p0.w = f2h(o[3]);
    p1.x = f2h(o[4]); p1.y = f2h(o[5]); p1.z = f2h(o[6]); p1.w = f2h(o[7]);
    *(ushort4*)&hb[(size_t)n * D1 + col] = p0;
    *(ushort4*)&hb[(size_t)n * D1 + col + 4] = p1;
  }
}

// ---------------- Layer-2 GEMM via MFMA (fp16) ----------------
// h2[50000, 32] = hb @ Wt2^T. h2l stored fp16 (gathered), h2r fp32.
__global__ __launch_bounds__(256) void k_gemm2m(
    const unsigned short* __restrict__ hb, const unsigned short* __restrict__ wt2,
    unsigned short* __restrict__ h2lh, float* __restrict__ h2r) {
  __shared__ unsigned short Bl[32 * PADK2];
  const int t = threadIdx.x;
  {
    const int n = t >> 3, k0 = (t & 7) * 32;
#pragma unroll
    for (int j = 0; j < 4; ++j)
      *(uint4*)&Bl[n * PADK2 + k0 + j * 8] = *(const uint4*)&wt2[n * 256 + k0 + j * 8];
  }
  __syncthreads();
  const int wave = t >> 6, lane = t & 63;
  const int fr = lane & 15, fq = lane >> 4;
  const int m0 = blockIdx.x * 128 + wave * 32;
  f32x4 acc[2][2] = {};
#pragma unroll
  for (int ks = 0; ks < 8; ++ks) {
    const int ko = ks * 32 + fq * 8;
    f16x8 a[2], b[2];
#pragma unroll
    for (int i = 0; i < 2; ++i) {
      int row = m0 + i * 16 + fr; if (row >= NN) row = NN - 1;
      a[i] = *(const f16x8*)&hb[(size_t)row * D1 + ko];
    }
#pragma unroll
    for (int j = 0; j < 2; ++j)
      b[j] = *(const f16x8*)&Bl[(j * 16 + fr) * PADK2 + ko];
#pragma unroll
    for (int i = 0; i < 2; ++i)
#pragma unroll
      for (int j = 0; j < 2; ++j)
        acc[i][j] = __builtin_amdgcn_mfma_f32_16x16x32_f16(a[i], b[j], acc[i][j], 0, 0, 0);
  }
#pragma unroll
  for (int i = 0; i < 2; ++i) {
    const int gm0 = m0 + i * 16 + fq * 4;
#pragma unroll
    for (int r = 0; r < 4; ++r) {
      const int gm = gm0 + r;
      if (gm < NN) {
        h2lh[(size_t)gm * C2 + fr] = f2h(acc[i][0][r]);
        h2r[(size_t)gm * C2 + fr] = acc[i][1][r];
      }
    }
  }
}

// ---------------- Layer-2 aggregation ----------------
__global__ __launch_bounds__(256) void k_agg2(
    const unsigned short* __restrict__ h2lh, const float* __restrict__ h2r,
    const int* __restrict__ offs, const int* __restrict__ csr,
    const float* __restrict__ att2, const float* __restrict__ b2,
    float* __restrict__ out) {
  const int wave = threadIdx.x >> 6;
  const int lane = threadIdx.x & 63;
  const int n = blockIdx.x * 4 + wave;
  if (n >= NN) return;
  const int c = lane & 15, g = lane >> 4;
  const float xr_v = h2r[(size_t)n * C2 + c];
  const float att_v = att2[c] * LOG2E;
  float l = 0.f, acc = 0.f;
  const int beg = offs[n], fin = offs[n + 1];
  for (int idx = beg + g; idx < fin; idx += 4) {
    int s = csr[idx];
    float xlv = h2f(h2lh[(size_t)s * C2 + c]);
    float v = xlv + xr_v;
    v = fmaxf(v, 0.2f * v);
    float sc0 = v * att_v;
    sc0 += __shfl_xor(sc0, 1);
    sc0 += __shfl_xor(sc0, 2);
    sc0 += __shfl_xor(sc0, 4);
    sc0 += __shfl_xor(sc0, 8);
    float p = exp2f(sc0);
    l += p;
    acc = fmaf(p, xlv, acc);
  }
  l += __shfl_xor(l, 16);   l += __shfl_xor(l, 32);
  acc += __shfl_xor(acc, 16); acc += __shfl_xor(acc, 32);
  float o = acc / (l + 1e-16f) + b2[c];
  o = o > 0.f ? o : 0.01f * o;
  if (lane < 16) out[(size_t)n * C2 + c] = o;
}

extern "C" void kernel_launch(void* const* d_in, const int* in_sizes, int n_in,
                              void* d_out, int out_size, void* d_ws, size_t ws_size,
                              hipStream_t stream) {
  const float* x    = (const float*)d_in[0];
  const int*   ei   = (const int*)d_in[1];
  const float* W1l  = (const float*)d_in[2];
  const float* W1r  = (const float*)d_in[3];
  const float* att1 = (const float*)d_in[4];
  const float* b1   = (const float*)d_in[5];
  const float* W2l  = (const float*)d_in[6];
  const float* W2r  = (const float*)d_in[7];
  const float* att2 = (const float*)d_in[8];
  const float* b2   = (const float*)d_in[9];
  float* out = (float*)d_out;

  // Workspace layout (~95 MB):
  unsigned short* xlh = (unsigned short*)d_ws;        // NN*D1 fp16
  unsigned short* xrh = xlh + (size_t)NN * D1;        // NN*D1 fp16
  unsigned short* hb  = xrh + (size_t)NN * D1;        // NN*D1 fp16
  int* deg  = (int*)(hb + (size_t)NN * D1);           // NN (becomes cursor)
  int* offs = deg + NN;                               // NN+1
  int* csr  = offs + NN + 1;                          // ET
  int* part = csr + ET;                               // NB
  unsigned short* xb = (unsigned short*)(part + NB);  // MPAD*F1 fp16
  unsigned short* wt = xb + (size_t)MPAD * F1;        // 512*128 fp16
  unsigned short* wt2 = wt + 512 * F1;                // 32*256 fp16
  unsigned short* h2lh = xlh;                         // alias: xlh dead after agg1
  float* h2r = (float*)(h2lh + (size_t)NN * C2);

  hipMemsetAsync(deg, 0, NN * sizeof(int), stream);
  k_prep<<<6544 + (ET + 255) / 256, 256, 0, stream>>>(
      x, W1l, W1r, W2l, W2r, ei, xb, wt, wt2, deg);
  k_gemm1m<<<dim3(MPAD / 128, 4), 256, 0, stream>>>(xb, wt, xlh, xrh);
  k_scan_part<<<NB, 256, 0, stream>>>(deg, part);
  k_scan_top<<<1, 256, 0, stream>>>(part, offs);
  k_scan_apply<<<NB, 256, 0, stream>>>(deg, part, offs);
  k_scatter<<<(ET + 255) / 256, 256, 0, stream>>>(ei, deg, csr);
  k_agg1<<<NN / 4, 256, 0, stream>>>(xlh, xrh, hb, offs, csr, att1, b1);
  k_gemm2m<<<(NN + 127) / 128, 256, 0, stream>>>(hb, wt2, h2lh, h2r);
  k_agg2<<<NN / 4, 256, 0, stream>>>(h2lh, h2r, offs, csr, att2, b2, out);
}